// Round 2
// baseline (1569.272 us; speedup 1.0000x reference)
//
#include <hip/hip_runtime.h>
#include <hip/hip_bf16.h>

// Problem constants (from setup_inputs: x = [2, 1024, 64] fp32)
constexpr int BB = 2;
constexpr int N  = 1024;
constexpr int C  = 64;
constexpr int S  = N * N;          // 1048576 = 2^20
constexpr int KSEL = S / 6;        // 174762 entries set to 1 per batch
constexpr int EQCAP = 4096;

// Order-preserving uint64 mapping of fp64 (monotone: a<b <=> key(a)<key(b))
__device__ __forceinline__ unsigned long long d2key(double d) {
    unsigned long long u = (unsigned long long)__double_as_longlong(d);
    return (u & 0x8000000000000000ULL) ? ~u : (u | 0x8000000000000000ULL);
}

// ---------------------------------------------------------------------------
// K1: per-row prep. One wave per row; lane = channel c.
__global__ __launch_bounds__(64) void k_prep(const float* __restrict__ x,
                                             double* __restrict__ xd,
                                             double* __restrict__ mean,
                                             double* __restrict__ rr,
                                             double* __restrict__ sinv) {
    int row = blockIdx.x;
    int c   = threadIdx.x;
    double v = (double)x[row * C + c];

    double s = v;
#pragma unroll
    for (int off = 32; off >= 1; off >>= 1) s += __shfl_xor(s, off);
    double m = s / 64.0;

    double w = v - m;
    double q = w * w;
#pragma unroll
    for (int off = 32; off >= 1; off >>= 1) q += __shfl_xor(q, off);

    double r = v * v;
#pragma unroll
    for (int off = 32; off >= 1; off >>= 1) r += __shfl_xor(r, off);

    xd[row * C + c] = v;
    if (c == 0) {
        mean[row] = m;
        rr[row]   = r;
        sinv[row] = 1.0 / sqrt(q);
    }
}

// ---------------------------------------------------------------------------
// K2: pairwise adjacencies (E = euclid, Ch = chebyshev, Cc = corrcoef)
__global__ __launch_bounds__(256) void k_pairwise(const double* __restrict__ xd,
                                                  const double* __restrict__ mean,
                                                  const double* __restrict__ rr,
                                                  const double* __restrict__ sinv,
                                                  double* __restrict__ E,
                                                  double* __restrict__ Ch,
                                                  double* __restrict__ Cc) {
    int b  = blockIdx.z;
    int i0 = blockIdx.y * 16;
    int j0 = blockIdx.x * 16;
    __shared__ double xi[16][65];
    __shared__ double xj[16][65];

    int t  = threadIdx.x;
    int r  = t >> 4;
    int c4 = (t & 15) << 2;
    const double* xb = xd + (size_t)b * N * C;
    {
        const double* pi = xb + (size_t)(i0 + r) * C + c4;
        const double* pj = xb + (size_t)(j0 + r) * C + c4;
        xi[r][c4]   = pi[0]; xi[r][c4+1] = pi[1]; xi[r][c4+2] = pi[2]; xi[r][c4+3] = pi[3];
        xj[r][c4]   = pj[0]; xj[r][c4+1] = pj[1]; xj[r][c4+2] = pj[2]; xj[r][c4+3] = pj[3];
    }
    __syncthreads();

    int ti = t >> 4, tj = t & 15;
    double dot = 0.0, m = 0.0;
#pragma unroll
    for (int c = 0; c < 64; ++c) {
        double a  = xi[ti][c];
        double bq = xj[tj][c];
        double d  = a - bq;
        m = fmax(m, fabs(d));
        dot = fma(a, bq, dot);
    }
    int gi = b * N + i0 + ti;
    int gj = b * N + j0 + tj;
    double d2 = rr[gi] + rr[gj] - 2.0 * dot;
    double e  = (i0 + ti == j0 + tj) ? 0.0 : sqrt(fmax(d2, 0.0));
    double cv = dot - 64.0 * mean[gi] * mean[gj];
    double cc = cv * sinv[gi] * sinv[gj];
    cc = fmin(1.0, fmax(-1.0, cc));

    size_t idx = (size_t)b * S + (size_t)(i0 + ti) * N + (j0 + tj);
    E[idx]  = e;
    Ch[idx] = m;
    Cc[idx] = cc;
}

// ---------------------------------------------------------------------------
// K3: C = scale * A * B^T (fp64). 128x64 tile, 256 thr, 8x4 acc/thread,
// K-chunk 16, register double-buffered staging.
__global__ __launch_bounds__(256) void k_gemm_nt(const double* __restrict__ A,
                                                 const double* __restrict__ Bm,
                                                 double* __restrict__ Cm,
                                                 double scale) {
    int b = blockIdx.z;
    const double* Ab = A  + (size_t)b * S;
    const double* Bb = Bm + (size_t)b * S;
    double*       Cb = Cm + (size_t)b * S;
    int i0 = blockIdx.y * 128, j0 = blockIdx.x * 64;

    __shared__ double At[128][17];
    __shared__ double Bt[64][17];

    int t  = threadIdx.x;
    int tx = t & 15, ty = t >> 4;
    int ar = t >> 1, ac = (t & 1) * 8;   // A stage: 128 rows x 16 k
    int br = t >> 2, bc = (t & 3) * 4;   // B stage: 64 rows x 16 k

    double acc[8][4] = {};
    const double* ap = Ab + (size_t)(i0 + ar) * N + ac;
    const double* bp = Bb + (size_t)(j0 + br) * N + bc;

    double pa[8], pb[4];
#pragma unroll
    for (int m = 0; m < 8; ++m) pa[m] = ap[m];
#pragma unroll
    for (int m = 0; m < 4; ++m) pb[m] = bp[m];

    for (int k0 = 0; k0 < N; k0 += 16) {
        __syncthreads();
#pragma unroll
        for (int m = 0; m < 8; ++m) At[ar][ac + m] = pa[m];
#pragma unroll
        for (int m = 0; m < 4; ++m) Bt[br][bc + m] = pb[m];
        __syncthreads();
        if (k0 + 16 < N) {
            ap += 16; bp += 16;
#pragma unroll
            for (int m = 0; m < 8; ++m) pa[m] = ap[m];
#pragma unroll
            for (int m = 0; m < 4; ++m) pb[m] = bp[m];
        }
#pragma unroll
        for (int kk = 0; kk < 16; ++kk) {
            double av[8], bv[4];
#pragma unroll
            for (int p = 0; p < 8; ++p) av[p] = At[ty + 16 * p][kk];
#pragma unroll
            for (int q = 0; q < 4; ++q) bv[q] = Bt[tx + 16 * q][kk];
#pragma unroll
            for (int p = 0; p < 8; ++p)
#pragma unroll
                for (int q = 0; q < 4; ++q)
                    acc[p][q] = fma(av[p], bv[q], acc[p][q]);
        }
    }
#pragma unroll
    for (int p = 0; p < 8; ++p)
#pragma unroll
        for (int q = 0; q < 4; ++q)
            Cb[(size_t)(i0 + ty + 16 * p) * N + (j0 + tx + 16 * q)] = acc[p][q] * scale;
}

// ---------------------------------------------------------------------------
// K5: W = A * B (fp64) + fused key32 epilogue. Same blocking as k_gemm_nt.
__global__ __launch_bounds__(256) void k_gemm_nn(const double* __restrict__ A,
                                                 const double* __restrict__ Bm,
                                                 double* __restrict__ Wm,
                                                 unsigned int* __restrict__ kq) {
    int b = blockIdx.z;
    const double* Ab = A  + (size_t)b * S;
    const double* Bb = Bm + (size_t)b * S;
    double*       Wb = Wm + (size_t)b * S;
    unsigned int* kb = kq + (size_t)b * S;
    int i0 = blockIdx.y * 128, j0 = blockIdx.x * 64;

    __shared__ double At[128][17];
    __shared__ double Bt[16][65];

    int t  = threadIdx.x;
    int tx = t & 15, ty = t >> 4;
    int ar = t >> 1, ac = (t & 1) * 8;   // A stage: 128 rows x 16 k
    int br = t >> 4, bc = (t & 15) * 4;  // B stage: 16 k x 64 cols

    double acc[8][4] = {};
    const double* ap = Ab + (size_t)(i0 + ar) * N + ac;
    const double* bp = Bb + (size_t)br * N + j0 + bc;

    double pa[8], pb[4];
#pragma unroll
    for (int m = 0; m < 8; ++m) pa[m] = ap[m];
#pragma unroll
    for (int m = 0; m < 4; ++m) pb[m] = bp[m];

    for (int k0 = 0; k0 < N; k0 += 16) {
        __syncthreads();
#pragma unroll
        for (int m = 0; m < 8; ++m) At[ar][ac + m] = pa[m];
#pragma unroll
        for (int m = 0; m < 4; ++m) Bt[br][bc + m] = pb[m];
        __syncthreads();
        if (k0 + 16 < N) {
            ap += 16; bp += (size_t)16 * N;
#pragma unroll
            for (int m = 0; m < 8; ++m) pa[m] = ap[m];
#pragma unroll
            for (int m = 0; m < 4; ++m) pb[m] = bp[m];
        }
#pragma unroll
        for (int kk = 0; kk < 16; ++kk) {
            double av[8], bv[4];
#pragma unroll
            for (int p = 0; p < 8; ++p) av[p] = At[ty + 16 * p][kk];
#pragma unroll
            for (int q = 0; q < 4; ++q) bv[q] = Bt[kk][tx + 16 * q];
#pragma unroll
            for (int p = 0; p < 8; ++p)
#pragma unroll
                for (int q = 0; q < 4; ++q)
                    acc[p][q] = fma(av[p], bv[q], acc[p][q]);
        }
    }
#pragma unroll
    for (int p = 0; p < 8; ++p)
#pragma unroll
        for (int q = 0; q < 4; ++q) {
            size_t idx = (size_t)(i0 + ty + 16 * p) * N + (j0 + tx + 16 * q);
            double w = acc[p][q];
            Wb[idx] = w;
            kb[idx] = (unsigned int)(d2key(w) >> 32);
        }
}

// ---------------------------------------------------------------------------
// K4: fp64 row softmax (1024 elems/row).
__global__ __launch_bounds__(256) void k_softmax(double* __restrict__ L) {
    int row = blockIdx.x;
    double* p = L + (size_t)row * N;
    int t = threadIdx.x;
    int wv = t >> 6, ln = t & 63;

    double v[4];
#pragma unroll
    for (int q = 0; q < 4; ++q) v[q] = p[t + 256 * q];

    double mx = fmax(fmax(v[0], v[1]), fmax(v[2], v[3]));
#pragma unroll
    for (int off = 32; off >= 1; off >>= 1) mx = fmax(mx, __shfl_xor(mx, off));
    __shared__ double redm[4];
    if (ln == 0) redm[wv] = mx;
    __syncthreads();
    mx = fmax(fmax(redm[0], redm[1]), fmax(redm[2], redm[3]));

    double s = 0.0;
#pragma unroll
    for (int q = 0; q < 4; ++q) { v[q] = exp(v[q] - mx); s += v[q]; }
#pragma unroll
    for (int off = 32; off >= 1; off >>= 1) s += __shfl_xor(s, off);
    __shared__ double reds[4];
    if (ln == 0) reds[wv] = s;
    __syncthreads();
    s = reds[0] + reds[1] + reds[2] + reds[3];

#pragma unroll
    for (int q = 0; q < 4; ++q) p[t + 256 * q] = v[q] / s;
}

// ---------------------------------------------------------------------------
// Radix select: 4 passes over precomputed 32-bit keys.
// st[2b] = accumulating threshold prefix (value < 2^32), st[2b+1] = remaining k.
// eqbuf: per batch {cnt, idx[EQCAP]}.

__global__ __launch_bounds__(256) void k_sel_init(unsigned long long* st,
                                                  int* __restrict__ hist,
                                                  int* __restrict__ eqbuf) {
    int t = threadIdx.x;
    hist[t] = 0; hist[256 + t] = 0;
    if (t < BB) {
        st[2 * t]     = 0ULL;
        st[2 * t + 1] = (unsigned long long)KSEL;
        eqbuf[t * (EQCAP + 1)] = 0;
    }
}

// 512 blocks x 256 thr; blocks [0,256) -> batch 0, [256,512) -> batch 1.
// Each thread: 4 x uint4 loads (16 keys).
__global__ __launch_bounds__(256) void k_sel_hist(const unsigned int* __restrict__ key32,
                                                  const unsigned long long* __restrict__ st,
                                                  int* __restrict__ hist, int shift) {
    __shared__ int lh[256];
    int t = threadIdx.x;
    lh[t] = 0;
    __syncthreads();
    int b  = blockIdx.x >> 8;
    int hb = blockIdx.x & 255;
    int hs = shift + 8;
    unsigned long long pref = st[2 * b] >> hs;     // u64 shift: hs==32 ok
    const uint4* k4 = (const uint4*)(key32 + (size_t)b * S);
    int tloc = hb * 256 + t;                       // 0..65535
#pragma unroll
    for (int it = 0; it < 4; ++it) {
        uint4 kv = k4[tloc + it * 65536];
        unsigned int ks[4] = {kv.x, kv.y, kv.z, kv.w};
#pragma unroll
        for (int c = 0; c < 4; ++c) {
            unsigned long long key = (unsigned long long)ks[c];
            bool match = (shift == 24) || ((key >> hs) == pref);
            if (match) atomicAdd(&lh[(int)((ks[c] >> shift) & 255u)], 1);
        }
    }
    __syncthreads();
    atomicAdd(&hist[b * 256 + t], lh[t]);
}

// Scan (threads 0..BB-1), then zero hist for the next pass.
__global__ __launch_bounds__(256) void k_sel_scan(unsigned long long* st,
                                                  int* __restrict__ hist, int shift) {
    int t = threadIdx.x;
    if (t < BB) {
        unsigned long long kneed = st[2 * t + 1];
        unsigned long long cum = 0;
        int bucket = 0;
        for (int i = 255; i >= 0; --i) {
            unsigned long long h = (unsigned long long)hist[t * 256 + i];
            if (cum + h >= kneed) { bucket = i; break; }
            cum += h;
        }
        st[2 * t]     |= ((unsigned long long)bucket) << shift;
        st[2 * t + 1]  = kneed - cum;
    }
    __syncthreads();
    hist[t] = 0; hist[256 + t] = 0;
}

// Collect batch-local indices of elements whose key32 equals the threshold.
__global__ __launch_bounds__(256) void k_sel_eq(const unsigned int* __restrict__ key32,
                                                const unsigned long long* __restrict__ st,
                                                int* __restrict__ eqbuf) {
    int tid = blockIdx.x * 256 + threadIdx.x;      // 0..131071
    const uint4* k4 = (const uint4*)key32;
    unsigned int T0 = (unsigned int)st[0];
    unsigned int T1 = (unsigned int)st[2];
#pragma unroll
    for (int it = 0; it < 4; ++it) {
        int idx4 = tid + it * 131072;              // 0..524287
        uint4 kv = k4[idx4];
        int b = idx4 >> 18;
        unsigned int T = b ? T1 : T0;
        int base = (idx4 << 2) & (S - 1);          // batch-local elem idx of .x
        unsigned int ks[4] = {kv.x, kv.y, kv.z, kv.w};
#pragma unroll
        for (int c = 0; c < 4; ++c) {
            if (ks[c] == T) {
                int p = atomicAdd(&eqbuf[b * (EQCAP + 1)], 1);
                if (p < EQCAP) eqbuf[b * (EQCAP + 1) + 1 + p] = base + c;
            }
        }
    }
}

// Final mask: 1 for key32 > T; exact fp64 (value, index) tie-break at == T.
__global__ __launch_bounds__(256) void k_sel_mask(const unsigned int* __restrict__ key32,
                                                  const double* __restrict__ W,
                                                  const unsigned long long* __restrict__ st,
                                                  const int* __restrict__ eqbuf,
                                                  float* __restrict__ out) {
    int tid = blockIdx.x * 256 + threadIdx.x;      // 0..131071
    const uint4* k4 = (const uint4*)key32;
    float4* out4 = (float4*)out;
#pragma unroll
    for (int it = 0; it < 4; ++it) {
        int idx4 = tid + it * 131072;
        uint4 kv = k4[idx4];
        int b = idx4 >> 18;
        unsigned int T = (unsigned int)st[2 * b];
        unsigned long long kneed = st[2 * b + 1];
        int base = (idx4 << 2) & (S - 1);
        unsigned int ks[4] = {kv.x, kv.y, kv.z, kv.w};
        float ov[4];
#pragma unroll
        for (int c = 0; c < 4; ++c) {
            float v = 0.0f;
            if (ks[c] > T) {
                v = 1.0f;
            } else if (ks[c] == T) {
                int s = base + c;
                int cnt = eqbuf[b * (EQCAP + 1)];
                if (cnt > EQCAP) cnt = EQCAP;
                double ws = W[(size_t)b * S + s];
                int ahead = 0;
                for (int e = 0; e < cnt; ++e) {
                    int j = eqbuf[b * (EQCAP + 1) + 1 + e];
                    double wj = W[(size_t)b * S + j];
                    ahead += (wj > ws || (wj == ws && j > s)) ? 1 : 0;
                }
                v = ((unsigned long long)ahead < kneed) ? 1.0f : 0.0f;
            }
            ov[c] = v;
        }
        out4[idx4] = make_float4(ov[0], ov[1], ov[2], ov[3]);
    }
}

// ---------------------------------------------------------------------------
extern "C" void kernel_launch(void* const* d_in, const int* in_sizes, int n_in,
                              void* d_out, int out_size, void* d_ws, size_t ws_size,
                              hipStream_t stream) {
    const float* x = (const float*)d_in[0];
    float* out = (float*)d_out;

    char* ws = (char*)d_ws;
    size_t off = 0;
    auto alloc = [&](size_t bytes) -> void* {
        void* p = ws + off;
        off += (bytes + 255) & ~(size_t)255;
        return p;
    };

    double* xd    = (double*)alloc((size_t)BB * N * C * sizeof(double));
    double* mean  = (double*)alloc((size_t)BB * N * sizeof(double));
    double* rr    = (double*)alloc((size_t)BB * N * sizeof(double));
    double* sinv  = (double*)alloc((size_t)BB * N * sizeof(double));
    double* E     = (double*)alloc((size_t)BB * S * sizeof(double));       // 16 MB
    double* Ch    = (double*)alloc((size_t)BB * S * sizeof(double));       // 16 MB
    double* Cc    = (double*)alloc((size_t)BB * S * sizeof(double));       // 16 MB
    double* L     = (double*)alloc((size_t)BB * S * sizeof(double));       // 16 MB
    unsigned int* key32 = (unsigned int*)alloc((size_t)BB * S * sizeof(unsigned int)); // 8 MB
    double* W     = E;  // E dead after gemm_nt -> reuse for weighted
    unsigned long long* st = (unsigned long long*)alloc(64);
    int* hist  = (int*)alloc((size_t)BB * 256 * sizeof(int));
    int* eqbuf = (int*)alloc((size_t)BB * (EQCAP + 1) * sizeof(int));

    // 1) per-row stats + fp64 upconvert
    k_prep<<<BB * N, 64, 0, stream>>>(x, xd, mean, rr, sinv);

    // 2) pairwise adjacencies
    k_pairwise<<<dim3(N / 16, N / 16, BB), 256, 0, stream>>>(xd, mean, rr, sinv, E, Ch, Cc);

    // 3) logits = (E @ Ch^T) * 1/8
    k_gemm_nt<<<dim3(N / 64, N / 128, BB), 256, 0, stream>>>(E, Ch, L, 0.125);

    // 4) softmax rows
    k_softmax<<<BB * N, 256, 0, stream>>>(L);

    // 5) weighted = attn @ Cc (into W == E) + fused key32 epilogue
    k_gemm_nn<<<dim3(N / 64, N / 128, BB), 256, 0, stream>>>(L, Cc, W, key32);

    // 6) exact top-K threshold: 4-pass radix select on key32
    k_sel_init<<<1, 256, 0, stream>>>(st, hist, eqbuf);
    for (int pass = 0; pass < 4; ++pass) {
        int shift = 24 - 8 * pass;
        k_sel_hist<<<512, 256, 0, stream>>>(key32, st, hist, shift);
        k_sel_scan<<<1, 256, 0, stream>>>(st, hist, shift);
    }

    // 7) tie collection + final mask
    k_sel_eq<<<512, 256, 0, stream>>>(key32, st, eqbuf);
    k_sel_mask<<<512, 256, 0, stream>>>(key32, W, st, eqbuf, out);
}

// Round 3
// 589.040 us; speedup vs baseline: 2.6641x; 2.6641x over previous
//
#include <hip/hip_runtime.h>
#include <hip/hip_bf16.h>

// Problem constants (from setup_inputs: x = [2, 1024, 64] fp32)
constexpr int BB = 2;
constexpr int N  = 1024;
constexpr int C  = 64;
constexpr int S  = N * N;          // 1048576 = 2^20
constexpr int KSEL = S / 6;        // 174762 entries set to 1 per batch
constexpr int EQCAP   = 65536;     // tie-list capacity per batch (exact dup rows!)
constexpr int ESTRIDE = 1 + 2 * EQCAP;

// Order-preserving uint64 mapping of fp64 (monotone: a<b <=> key(a)<key(b))
__device__ __forceinline__ unsigned long long d2key(double d) {
    unsigned long long u = (unsigned long long)__double_as_longlong(d);
    return (u & 0x8000000000000000ULL) ? ~u : (u | 0x8000000000000000ULL);
}

// ---------------------------------------------------------------------------
// K1: per-row prep. Wave per row, grid-strided (32 wgs; dispatch-rate safe).
__global__ __launch_bounds__(256) void k_prep(const float* __restrict__ x,
                                              double* __restrict__ xd,
                                              double* __restrict__ mean,
                                              double* __restrict__ rr,
                                              double* __restrict__ sinv) {
    int wv = (blockIdx.x << 2) + (threadIdx.x >> 6);   // 0..127
    int c  = threadIdx.x & 63;
    for (int row = wv; row < BB * N; row += 128) {
        double v = (double)x[row * C + c];

        double s = v;
#pragma unroll
        for (int off = 32; off >= 1; off >>= 1) s += __shfl_xor(s, off);
        double m = s / 64.0;

        double w = v - m;
        double q = w * w;
#pragma unroll
        for (int off = 32; off >= 1; off >>= 1) q += __shfl_xor(q, off);

        double r = v * v;
#pragma unroll
        for (int off = 32; off >= 1; off >>= 1) r += __shfl_xor(r, off);

        xd[row * C + c] = v;
        if (c == 0) {
            mean[row] = m;
            rr[row]   = r;
            sinv[row] = 1.0 / sqrt(q);
        }
    }
}

// ---------------------------------------------------------------------------
// K2: pairwise adjacencies, 64x64 tile per wg (512 wgs), 4x4 pairs/thread.
__global__ __launch_bounds__(256) void k_pairwise(const double* __restrict__ xd,
                                                  const double* __restrict__ mean,
                                                  const double* __restrict__ rr,
                                                  const double* __restrict__ sinv,
                                                  double* __restrict__ E,
                                                  double* __restrict__ Ch,
                                                  double* __restrict__ Cc) {
    int b  = blockIdx.z;
    int i0 = blockIdx.y * 64;
    int j0 = blockIdx.x * 64;
    __shared__ double xi[64][65];
    __shared__ double xj[64][65];

    int t  = threadIdx.x;
    int r  = t >> 2;
    int cb = (t & 3) * 16;
    const double* xb = xd + (size_t)b * N * C;
    {
        const double* pi = xb + (size_t)(i0 + r) * C + cb;
        const double* pj = xb + (size_t)(j0 + r) * C + cb;
#pragma unroll
        for (int m = 0; m < 16; ++m) { xi[r][cb + m] = pi[m]; xj[r][cb + m] = pj[m]; }
    }
    __syncthreads();

    int ty = t >> 4, tx = t & 15;
    double adot[4][4] = {};
    double amax[4][4] = {};
#pragma unroll 8
    for (int c = 0; c < 64; ++c) {
        double ai[4], aj[4];
#pragma unroll
        for (int p = 0; p < 4; ++p) ai[p] = xi[ty + 16 * p][c];
#pragma unroll
        for (int q = 0; q < 4; ++q) aj[q] = xj[tx + 16 * q][c];
#pragma unroll
        for (int p = 0; p < 4; ++p)
#pragma unroll
            for (int q = 0; q < 4; ++q) {
                double d = ai[p] - aj[q];
                amax[p][q] = fmax(amax[p][q], fabs(d));
                adot[p][q] = fma(ai[p], aj[q], adot[p][q]);
            }
    }

#pragma unroll
    for (int p = 0; p < 4; ++p) {
        int ii = i0 + ty + 16 * p;
        int gi = b * N + ii;
        double rri = rr[gi], mi = mean[gi], si = sinv[gi];
#pragma unroll
        for (int q = 0; q < 4; ++q) {
            int jj = j0 + tx + 16 * q;
            int gj = b * N + jj;
            double dot = adot[p][q];
            double d2  = rri + rr[gj] - 2.0 * dot;
            double e   = (ii == jj) ? 0.0 : sqrt(fmax(d2, 0.0));
            double cc  = (dot - 64.0 * mi * mean[gj]) * si * sinv[gj];
            cc = fmin(1.0, fmax(-1.0, cc));
            size_t idx = (size_t)b * S + (size_t)ii * N + jj;
            E[idx]  = e;
            Ch[idx] = amax[p][q];
            Cc[idx] = cc;
        }
    }
}

// ---------------------------------------------------------------------------
// K3: C = scale * A * B^T (fp64). 128x64 tile, 256 thr, 8x4 acc/thread,
// K-chunk 16, register double-buffered staging.
__global__ __launch_bounds__(256) void k_gemm_nt(const double* __restrict__ A,
                                                 const double* __restrict__ Bm,
                                                 double* __restrict__ Cm,
                                                 double scale) {
    int b = blockIdx.z;
    const double* Ab = A  + (size_t)b * S;
    const double* Bb = Bm + (size_t)b * S;
    double*       Cb = Cm + (size_t)b * S;
    int i0 = blockIdx.y * 128, j0 = blockIdx.x * 64;

    __shared__ double At[128][17];
    __shared__ double Bt[64][17];

    int t  = threadIdx.x;
    int tx = t & 15, ty = t >> 4;
    int ar = t >> 1, ac = (t & 1) * 8;   // A stage: 128 rows x 16 k
    int br = t >> 2, bc = (t & 3) * 4;   // B stage: 64 rows x 16 k

    double acc[8][4] = {};
    const double* ap = Ab + (size_t)(i0 + ar) * N + ac;
    const double* bp = Bb + (size_t)(j0 + br) * N + bc;

    double pa[8], pb[4];
#pragma unroll
    for (int m = 0; m < 8; ++m) pa[m] = ap[m];
#pragma unroll
    for (int m = 0; m < 4; ++m) pb[m] = bp[m];

    for (int k0 = 0; k0 < N; k0 += 16) {
        __syncthreads();
#pragma unroll
        for (int m = 0; m < 8; ++m) At[ar][ac + m] = pa[m];
#pragma unroll
        for (int m = 0; m < 4; ++m) Bt[br][bc + m] = pb[m];
        __syncthreads();
        if (k0 + 16 < N) {
            ap += 16; bp += 16;
#pragma unroll
            for (int m = 0; m < 8; ++m) pa[m] = ap[m];
#pragma unroll
            for (int m = 0; m < 4; ++m) pb[m] = bp[m];
        }
#pragma unroll
        for (int kk = 0; kk < 16; ++kk) {
            double av[8], bv[4];
#pragma unroll
            for (int p = 0; p < 8; ++p) av[p] = At[ty + 16 * p][kk];
#pragma unroll
            for (int q = 0; q < 4; ++q) bv[q] = Bt[tx + 16 * q][kk];
#pragma unroll
            for (int p = 0; p < 8; ++p)
#pragma unroll
                for (int q = 0; q < 4; ++q)
                    acc[p][q] = fma(av[p], bv[q], acc[p][q]);
        }
    }
#pragma unroll
    for (int p = 0; p < 8; ++p)
#pragma unroll
        for (int q = 0; q < 4; ++q)
            Cb[(size_t)(i0 + ty + 16 * p) * N + (j0 + tx + 16 * q)] = acc[p][q] * scale;
}

// ---------------------------------------------------------------------------
// K5: W = A * B (fp64) + fused key32 epilogue. Same blocking as k_gemm_nt.
__global__ __launch_bounds__(256) void k_gemm_nn(const double* __restrict__ A,
                                                 const double* __restrict__ Bm,
                                                 double* __restrict__ Wm,
                                                 unsigned int* __restrict__ kq) {
    int b = blockIdx.z;
    const double* Ab = A  + (size_t)b * S;
    const double* Bb = Bm + (size_t)b * S;
    double*       Wb = Wm + (size_t)b * S;
    unsigned int* kb = kq + (size_t)b * S;
    int i0 = blockIdx.y * 128, j0 = blockIdx.x * 64;

    __shared__ double At[128][17];
    __shared__ double Bt[16][65];

    int t  = threadIdx.x;
    int tx = t & 15, ty = t >> 4;
    int ar = t >> 1, ac = (t & 1) * 8;   // A stage: 128 rows x 16 k
    int br = t >> 4, bc = (t & 15) * 4;  // B stage: 16 k x 64 cols

    double acc[8][4] = {};
    const double* ap = Ab + (size_t)(i0 + ar) * N + ac;
    const double* bp = Bb + (size_t)br * N + j0 + bc;

    double pa[8], pb[4];
#pragma unroll
    for (int m = 0; m < 8; ++m) pa[m] = ap[m];
#pragma unroll
    for (int m = 0; m < 4; ++m) pb[m] = bp[m];

    for (int k0 = 0; k0 < N; k0 += 16) {
        __syncthreads();
#pragma unroll
        for (int m = 0; m < 8; ++m) At[ar][ac + m] = pa[m];
#pragma unroll
        for (int m = 0; m < 4; ++m) Bt[br][bc + m] = pb[m];
        __syncthreads();
        if (k0 + 16 < N) {
            ap += 16; bp += (size_t)16 * N;
#pragma unroll
            for (int m = 0; m < 8; ++m) pa[m] = ap[m];
#pragma unroll
            for (int m = 0; m < 4; ++m) pb[m] = bp[m];
        }
#pragma unroll
        for (int kk = 0; kk < 16; ++kk) {
            double av[8], bv[4];
#pragma unroll
            for (int p = 0; p < 8; ++p) av[p] = At[ty + 16 * p][kk];
#pragma unroll
            for (int q = 0; q < 4; ++q) bv[q] = Bt[kk][tx + 16 * q];
#pragma unroll
            for (int p = 0; p < 8; ++p)
#pragma unroll
                for (int q = 0; q < 4; ++q)
                    acc[p][q] = fma(av[p], bv[q], acc[p][q]);
        }
    }
#pragma unroll
    for (int p = 0; p < 8; ++p)
#pragma unroll
        for (int q = 0; q < 4; ++q) {
            size_t idx = (size_t)(i0 + ty + 16 * p) * N + (j0 + tx + 16 * q);
            double w = acc[p][q];
            Wb[idx] = w;
            kb[idx] = (unsigned int)(d2key(w) >> 32);
        }
}

// ---------------------------------------------------------------------------
// K4: fp64 row softmax. Wave per row, shuffle-only; grid 512 wgs.
__global__ __launch_bounds__(256) void k_softmax(double* __restrict__ L) {
    int row = (blockIdx.x << 2) + (threadIdx.x >> 6);  // 0..2047
    int ln  = threadIdx.x & 63;
    double* p = L + (size_t)row * N;

    double v[16];
#pragma unroll
    for (int q = 0; q < 16; ++q) v[q] = p[ln + 64 * q];

    double mx = v[0];
#pragma unroll
    for (int q = 1; q < 16; ++q) mx = fmax(mx, v[q]);
#pragma unroll
    for (int off = 32; off >= 1; off >>= 1) mx = fmax(mx, __shfl_xor(mx, off));

    double s = 0.0;
#pragma unroll
    for (int q = 0; q < 16; ++q) { v[q] = exp(v[q] - mx); s += v[q]; }
#pragma unroll
    for (int off = 32; off >= 1; off >>= 1) s += __shfl_xor(s, off);

#pragma unroll
    for (int q = 0; q < 16; ++q) p[ln + 64 * q] = v[q] / s;
}

// ---------------------------------------------------------------------------
// Radix select stage A: 4 passes over key32.
// st[2b] = accumulating threshold prefix, st[2b+1] = remaining k.

__global__ __launch_bounds__(256) void k_sel_init(unsigned long long* st,
                                                  int* __restrict__ hist,
                                                  int* __restrict__ eqbuf,
                                                  unsigned int* __restrict__ sc) {
    int t = threadIdx.x;
    hist[t] = 0; hist[256 + t] = 0;
    if (t < BB) {
        st[2 * t]     = 0ULL;
        st[2 * t + 1] = (unsigned long long)KSEL;
        eqbuf[t * ESTRIDE] = 0;
        sc[2 * t] = 0u; sc[2 * t + 1] = 0u;
    }
}

// 512 blocks x 256 thr; blocks [0,256) -> batch 0, [256,512) -> batch 1.
__global__ __launch_bounds__(256) void k_sel_hist(const unsigned int* __restrict__ key32,
                                                  const unsigned long long* __restrict__ st,
                                                  int* __restrict__ hist, int shift) {
    __shared__ int lh[256];
    int t = threadIdx.x;
    lh[t] = 0;
    __syncthreads();
    int b  = blockIdx.x >> 8;
    int hb = blockIdx.x & 255;
    int hs = shift + 8;
    unsigned long long pref = st[2 * b] >> hs;
    const uint4* k4 = (const uint4*)(key32 + (size_t)b * S);
    int tloc = hb * 256 + t;
#pragma unroll
    for (int it = 0; it < 4; ++it) {
        uint4 kv = k4[tloc + it * 65536];
        unsigned int ks[4] = {kv.x, kv.y, kv.z, kv.w};
#pragma unroll
        for (int c = 0; c < 4; ++c) {
            unsigned long long key = (unsigned long long)ks[c];
            bool match = (shift == 24) || ((key >> hs) == pref);
            if (match) atomicAdd(&lh[(int)((ks[c] >> shift) & 255u)], 1);
        }
    }
    __syncthreads();
    atomicAdd(&hist[b * 256 + t], lh[t]);
}

__global__ __launch_bounds__(256) void k_sel_scan(unsigned long long* st,
                                                  int* __restrict__ hist, int shift) {
    int t = threadIdx.x;
    if (t < BB) {
        unsigned long long kneed = st[2 * t + 1];
        unsigned long long cum = 0;
        int bucket = 0;
        for (int i = 255; i >= 0; --i) {
            unsigned long long h = (unsigned long long)hist[t * 256 + i];
            if (cum + h >= kneed) { bucket = i; break; }
            cum += h;
        }
        st[2 * t]     |= ((unsigned long long)bucket) << shift;
        st[2 * t + 1]  = kneed - cum;
    }
    __syncthreads();
    hist[t] = 0; hist[256 + t] = 0;
}

// Stage B: collect (low32, idx) for key32 == T32. 256 wgs grid-strided.
__global__ __launch_bounds__(256) void k_sel_eq(const unsigned int* __restrict__ key32,
                                                const double* __restrict__ W,
                                                const unsigned long long* __restrict__ st,
                                                int* __restrict__ eqbuf) {
    int tid = blockIdx.x * 256 + threadIdx.x;      // 0..65535
    const uint4* k4 = (const uint4*)key32;
    unsigned int T0 = (unsigned int)st[0];
    unsigned int T1 = (unsigned int)st[2];
#pragma unroll
    for (int it = 0; it < 8; ++it) {
        int idx4 = tid + it * 65536;               // 0..524287
        uint4 kv = k4[idx4];
        int b = idx4 >> 18;
        unsigned int T = b ? T1 : T0;
        int base = (idx4 << 2) & (S - 1);
        unsigned int ks[4] = {kv.x, kv.y, kv.z, kv.w};
#pragma unroll
        for (int c = 0; c < 4; ++c) {
            if (ks[c] == T) {
                int p = atomicAdd(&eqbuf[b * ESTRIDE], 1);
                if (p < EQCAP) {
                    int s = base + c;
                    unsigned int low = (unsigned int)d2key(W[(size_t)b * S + s]);
                    eqbuf[b * ESTRIDE + 1 + 2 * p] = (int)low;
                    eqbuf[b * ESTRIDE + 2 + 2 * p] = s;
                }
            }
        }
    }
}

// Stage C: exact refinement. One block per batch. 4 radix passes on low32,
// then 3 radix passes on the (unique) flat index -> (TL, sCut).
__global__ __launch_bounds__(256) void k_sel_refine(const unsigned long long* __restrict__ st,
                                                    const int* __restrict__ eqbuf,
                                                    unsigned int* __restrict__ sc) {
    int b = blockIdx.x;
    int t = threadIdx.x;
    const int* eb = eqbuf + b * ESTRIDE;
    int cnt = eb[0];
    if (cnt > EQCAP) cnt = EQCAP;

    __shared__ int hist[256];
    __shared__ unsigned int sh_pref;
    __shared__ unsigned long long sh_kneed;
    if (t == 0) { sh_pref = 0u; sh_kneed = st[2 * b + 1]; }
    __syncthreads();

    // --- low32 select (4 passes, msb first)
    for (int shift = 24; shift >= 0; shift -= 8) {
        hist[t] = 0;
        __syncthreads();
        unsigned int pref = sh_pref;
        for (int e = t; e < cnt; e += 256) {
            unsigned int low = (unsigned int)eb[1 + 2 * e];
            bool match = (shift == 24) || (((low ^ pref) >> (shift + 8)) == 0u);
            if (match) atomicAdd(&hist[(low >> shift) & 255u], 1);
        }
        __syncthreads();
        if (t == 0) {
            unsigned long long kneed = sh_kneed, cum = 0;
            int bucket = 0;
            for (int i = 255; i >= 0; --i) {
                unsigned long long h = (unsigned long long)hist[i];
                if (cum + h >= kneed) { bucket = i; break; }
                cum += h;
            }
            sh_pref  = pref | ((unsigned int)bucket << shift);
            sh_kneed = kneed - cum;
        }
        __syncthreads();
    }
    unsigned int TL = sh_pref;
    __syncthreads();
    if (t == 0) sh_pref = 0u;
    __syncthreads();

    // --- index select among full-key ties (3 passes; indices < 2^20, unique)
    for (int shift = 16; shift >= 0; shift -= 8) {
        hist[t] = 0;
        __syncthreads();
        unsigned int pref = sh_pref;
        for (int e = t; e < cnt; e += 256) {
            unsigned int low = (unsigned int)eb[1 + 2 * e];
            if (low != TL) continue;
            unsigned int idx = (unsigned int)eb[2 + 2 * e];
            bool match = (shift == 16) || (((idx ^ pref) >> (shift + 8)) == 0u);
            if (match) atomicAdd(&hist[(idx >> shift) & 255u], 1);
        }
        __syncthreads();
        if (t == 0) {
            unsigned long long kneed = sh_kneed, cum = 0;
            int bucket = 0;
            for (int i = 255; i >= 0; --i) {
                unsigned long long h = (unsigned long long)hist[i];
                if (cum + h >= kneed) { bucket = i; break; }
                cum += h;
            }
            sh_pref  = pref | ((unsigned int)bucket << shift);
            sh_kneed = kneed - cum;
        }
        __syncthreads();
    }
    if (t == 0) {
        sc[2 * b]     = TL;       // low32 threshold
        sc[2 * b + 1] = sh_pref;  // exact index cutoff: selected iff idx >= sCut
    }
}

// Final mask: pure streaming, no loops. 256 wgs.
__global__ __launch_bounds__(256) void k_sel_mask(const unsigned int* __restrict__ key32,
                                                  const double* __restrict__ W,
                                                  const unsigned long long* __restrict__ st,
                                                  const unsigned int* __restrict__ sc,
                                                  float* __restrict__ out) {
    int tid = blockIdx.x * 256 + threadIdx.x;      // 0..65535
    const uint4* k4 = (const uint4*)key32;
    float4* out4 = (float4*)out;
    unsigned int T0 = (unsigned int)st[0];
    unsigned int T1 = (unsigned int)st[2];
#pragma unroll
    for (int it = 0; it < 8; ++it) {
        int idx4 = tid + it * 65536;
        uint4 kv = k4[idx4];
        int b = idx4 >> 18;
        unsigned int T    = b ? T1 : T0;
        unsigned int TL   = sc[2 * b];
        unsigned int sCut = sc[2 * b + 1];
        int base = (idx4 << 2) & (S - 1);
        unsigned int ks[4] = {kv.x, kv.y, kv.z, kv.w};
        float ov[4];
#pragma unroll
        for (int c = 0; c < 4; ++c) {
            float v = 0.0f;
            if (ks[c] > T) {
                v = 1.0f;
            } else if (ks[c] == T) {
                int s = base + c;
                unsigned int low = (unsigned int)d2key(W[(size_t)b * S + s]);
                v = (low > TL || (low == TL && (unsigned int)s >= sCut)) ? 1.0f : 0.0f;
            }
            ov[c] = v;
        }
        out4[idx4] = make_float4(ov[0], ov[1], ov[2], ov[3]);
    }
}

// ---------------------------------------------------------------------------
extern "C" void kernel_launch(void* const* d_in, const int* in_sizes, int n_in,
                              void* d_out, int out_size, void* d_ws, size_t ws_size,
                              hipStream_t stream) {
    const float* x = (const float*)d_in[0];
    float* out = (float*)d_out;

    char* ws = (char*)d_ws;
    size_t off = 0;
    auto alloc = [&](size_t bytes) -> void* {
        void* p = ws + off;
        off += (bytes + 255) & ~(size_t)255;
        return p;
    };

    double* xd    = (double*)alloc((size_t)BB * N * C * sizeof(double));
    double* mean  = (double*)alloc((size_t)BB * N * sizeof(double));
    double* rr    = (double*)alloc((size_t)BB * N * sizeof(double));
    double* sinv  = (double*)alloc((size_t)BB * N * sizeof(double));
    double* E     = (double*)alloc((size_t)BB * S * sizeof(double));       // 16 MB
    double* Ch    = (double*)alloc((size_t)BB * S * sizeof(double));       // 16 MB
    double* Cc    = (double*)alloc((size_t)BB * S * sizeof(double));       // 16 MB
    double* L     = (double*)alloc((size_t)BB * S * sizeof(double));       // 16 MB
    unsigned int* key32 = (unsigned int*)alloc((size_t)BB * S * sizeof(unsigned int)); // 8 MB
    double* W     = E;  // E dead after gemm_nt -> reuse for weighted
    unsigned long long* st = (unsigned long long*)alloc(64);
    unsigned int* sc = (unsigned int*)alloc(64);
    int* hist  = (int*)alloc((size_t)BB * 256 * sizeof(int));
    int* eqbuf = (int*)alloc((size_t)BB * ESTRIDE * sizeof(int));          // ~1 MB

    // 1) per-row stats + fp64 upconvert
    k_prep<<<32, 256, 0, stream>>>(x, xd, mean, rr, sinv);

    // 2) pairwise adjacencies (64x64 tiles, 512 wgs)
    k_pairwise<<<dim3(N / 64, N / 64, BB), 256, 0, stream>>>(xd, mean, rr, sinv, E, Ch, Cc);

    // 3) logits = (E @ Ch^T) * 1/8
    k_gemm_nt<<<dim3(N / 64, N / 128, BB), 256, 0, stream>>>(E, Ch, L, 0.125);

    // 4) softmax rows (wave per row, 512 wgs)
    k_softmax<<<512, 256, 0, stream>>>(L);

    // 5) weighted = attn @ Cc (into W == E) + fused key32 epilogue
    k_gemm_nn<<<dim3(N / 64, N / 128, BB), 256, 0, stream>>>(L, Cc, W, key32);

    // 6) stage A: 4-pass radix select on key32
    k_sel_init<<<1, 256, 0, stream>>>(st, hist, eqbuf, sc);
    for (int pass = 0; pass < 4; ++pass) {
        int shift = 24 - 8 * pass;
        k_sel_hist<<<512, 256, 0, stream>>>(key32, st, hist, shift);
        k_sel_scan<<<1, 256, 0, stream>>>(st, hist, shift);
    }

    // 7) stage B+C: exact tie refinement (no per-thread loops anywhere)
    k_sel_eq<<<256, 256, 0, stream>>>(key32, W, st, eqbuf);
    k_sel_refine<<<BB, 256, 0, stream>>>(st, eqbuf, sc);

    // 8) final mask (pure streaming)
    k_sel_mask<<<256, 256, 0, stream>>>(key32, W, st, sc, out);
}

// Round 4
// 583.847 us; speedup vs baseline: 2.6878x; 1.0089x over previous
//
#include <hip/hip_runtime.h>
#include <hip/hip_bf16.h>

// Problem constants (from setup_inputs: x = [2, 1024, 64] fp32)
constexpr int BB = 2;
constexpr int N  = 1024;
constexpr int C  = 64;
constexpr int S  = N * N;          // 1048576 = 2^20
constexpr int KSEL = S / 6;        // 174762 entries set to 1 per batch
constexpr int EQCAP   = 65536;     // tie-list capacity per batch (exact dup rows!)
constexpr int ESTRIDE = 1 + 2 * EQCAP;

// Order-preserving uint64 mapping of fp64 (monotone: a<b <=> key(a)<key(b))
__device__ __forceinline__ unsigned long long d2key(double d) {
    unsigned long long u = (unsigned long long)__double_as_longlong(d);
    return (u & 0x8000000000000000ULL) ? ~u : (u | 0x8000000000000000ULL);
}

// ---------------------------------------------------------------------------
// K1: per-row prep. Wave per row, grid-strided (32 wgs; dispatch-rate safe).
__global__ __launch_bounds__(256) void k_prep(const float* __restrict__ x,
                                              double* __restrict__ xd,
                                              double* __restrict__ mean,
                                              double* __restrict__ rr,
                                              double* __restrict__ sinv) {
    int wv = (blockIdx.x << 2) + (threadIdx.x >> 6);   // 0..127
    int c  = threadIdx.x & 63;
    for (int row = wv; row < BB * N; row += 128) {
        double v = (double)x[row * C + c];

        double s = v;
#pragma unroll
        for (int off = 32; off >= 1; off >>= 1) s += __shfl_xor(s, off);
        double m = s / 64.0;

        double w = v - m;
        double q = w * w;
#pragma unroll
        for (int off = 32; off >= 1; off >>= 1) q += __shfl_xor(q, off);

        double r = v * v;
#pragma unroll
        for (int off = 32; off >= 1; off >>= 1) r += __shfl_xor(r, off);

        xd[row * C + c] = v;
        if (c == 0) {
            mean[row] = m;
            rr[row]   = r;
            sinv[row] = 1.0 / sqrt(q);
        }
    }
}

// ---------------------------------------------------------------------------
// K2: pairwise adjacencies, 64x64 tile per wg (512 wgs), 4x4 pairs/thread.
__global__ __launch_bounds__(256) void k_pairwise(const double* __restrict__ xd,
                                                  const double* __restrict__ mean,
                                                  const double* __restrict__ rr,
                                                  const double* __restrict__ sinv,
                                                  double* __restrict__ E,
                                                  double* __restrict__ Ch,
                                                  double* __restrict__ Cc) {
    int b  = blockIdx.z;
    int i0 = blockIdx.y * 64;
    int j0 = blockIdx.x * 64;
    __shared__ double xi[64][65];
    __shared__ double xj[64][65];

    int t  = threadIdx.x;
    int r  = t >> 2;
    int cb = (t & 3) * 16;
    const double* xb = xd + (size_t)b * N * C;
    {
        const double* pi = xb + (size_t)(i0 + r) * C + cb;
        const double* pj = xb + (size_t)(j0 + r) * C + cb;
#pragma unroll
        for (int m = 0; m < 16; ++m) { xi[r][cb + m] = pi[m]; xj[r][cb + m] = pj[m]; }
    }
    __syncthreads();

    int ty = t >> 4, tx = t & 15;
    double adot[4][4] = {};
    double amax[4][4] = {};
#pragma unroll 8
    for (int c = 0; c < 64; ++c) {
        double ai[4], aj[4];
#pragma unroll
        for (int p = 0; p < 4; ++p) ai[p] = xi[ty + 16 * p][c];
#pragma unroll
        for (int q = 0; q < 4; ++q) aj[q] = xj[tx + 16 * q][c];
#pragma unroll
        for (int p = 0; p < 4; ++p)
#pragma unroll
            for (int q = 0; q < 4; ++q) {
                double d = ai[p] - aj[q];
                amax[p][q] = fmax(amax[p][q], fabs(d));
                adot[p][q] = fma(ai[p], aj[q], adot[p][q]);
            }
    }

#pragma unroll
    for (int p = 0; p < 4; ++p) {
        int ii = i0 + ty + 16 * p;
        int gi = b * N + ii;
        double rri = rr[gi], mi = mean[gi], si = sinv[gi];
#pragma unroll
        for (int q = 0; q < 4; ++q) {
            int jj = j0 + tx + 16 * q;
            int gj = b * N + jj;
            double dot = adot[p][q];
            double d2  = rri + rr[gj] - 2.0 * dot;
            double e   = (ii == jj) ? 0.0 : sqrt(fmax(d2, 0.0));
            double cc  = (dot - 64.0 * mi * mean[gj]) * si * sinv[gj];
            cc = fmin(1.0, fmax(-1.0, cc));
            size_t idx = (size_t)b * S + (size_t)ii * N + jj;
            E[idx]  = e;
            Ch[idx] = amax[p][q];
            Cc[idx] = cc;
        }
    }
}

// ---------------------------------------------------------------------------
// K3: C = scale * A * B^T (fp64). 64x64 tile (512 wgs -> 2 blocks/CU),
// 256 thr, 4x4 acc/thread, BK=32, register double-buffered staging.
__global__ __launch_bounds__(256) void k_gemm_nt(const double* __restrict__ A,
                                                 const double* __restrict__ Bm,
                                                 double* __restrict__ Cm,
                                                 double scale) {
    int b = blockIdx.z;
    const double* Ab = A  + (size_t)b * S;
    const double* Bb = Bm + (size_t)b * S;
    double*       Cb = Cm + (size_t)b * S;
    int i0 = blockIdx.y * 64, j0 = blockIdx.x * 64;

    __shared__ double At[64][33];
    __shared__ double Bt[64][33];

    int t  = threadIdx.x;
    int tx = t & 15, ty = t >> 4;
    int sr = t >> 2, sc = (t & 3) * 8;   // stage: 64 rows x 32 k, 8 dbl/thread

    double acc[4][4] = {};
    const double* ap = Ab + (size_t)(i0 + sr) * N + sc;
    const double* bp = Bb + (size_t)(j0 + sr) * N + sc;

    double pa[8], pb[8];
#pragma unroll
    for (int m = 0; m < 8; ++m) { pa[m] = ap[m]; pb[m] = bp[m]; }

    for (int k0 = 0; k0 < N; k0 += 32) {
        __syncthreads();
#pragma unroll
        for (int m = 0; m < 8; ++m) { At[sr][sc + m] = pa[m]; Bt[sr][sc + m] = pb[m]; }
        __syncthreads();
        if (k0 + 32 < N) {
            ap += 32; bp += 32;
#pragma unroll
            for (int m = 0; m < 8; ++m) { pa[m] = ap[m]; pb[m] = bp[m]; }
        }
#pragma unroll
        for (int kk = 0; kk < 32; ++kk) {
            double av[4], bv[4];
#pragma unroll
            for (int p = 0; p < 4; ++p) av[p] = At[ty + 16 * p][kk];
#pragma unroll
            for (int q = 0; q < 4; ++q) bv[q] = Bt[tx + 16 * q][kk];
#pragma unroll
            for (int p = 0; p < 4; ++p)
#pragma unroll
                for (int q = 0; q < 4; ++q)
                    acc[p][q] = fma(av[p], bv[q], acc[p][q]);
        }
    }
#pragma unroll
    for (int p = 0; p < 4; ++p)
#pragma unroll
        for (int q = 0; q < 4; ++q)
            Cb[(size_t)(i0 + ty + 16 * p) * N + (j0 + tx + 16 * q)] = acc[p][q] * scale;
}

// ---------------------------------------------------------------------------
// K5: W = A * B (fp64) + fused key32 epilogue. 64x64 tile, BK=32.
__global__ __launch_bounds__(256) void k_gemm_nn(const double* __restrict__ A,
                                                 const double* __restrict__ Bm,
                                                 double* __restrict__ Wm,
                                                 unsigned int* __restrict__ kq) {
    int b = blockIdx.z;
    const double* Ab = A  + (size_t)b * S;
    const double* Bb = Bm + (size_t)b * S;
    double*       Wb = Wm + (size_t)b * S;
    unsigned int* kb = kq + (size_t)b * S;
    int i0 = blockIdx.y * 64, j0 = blockIdx.x * 64;

    __shared__ double At[64][33];
    __shared__ double Bt[32][65];

    int t  = threadIdx.x;
    int tx = t & 15, ty = t >> 4;
    int sr = t >> 2, sc = (t & 3) * 8;   // A stage: 64 rows x 32 k
    int br = t >> 3, bc = (t & 7) * 8;   // B stage: 32 k x 64 cols

    double acc[4][4] = {};
    const double* ap = Ab + (size_t)(i0 + sr) * N + sc;
    const double* bp = Bb + (size_t)br * N + j0 + bc;

    double pa[8], pb[8];
#pragma unroll
    for (int m = 0; m < 8; ++m) { pa[m] = ap[m]; pb[m] = bp[m]; }

    for (int k0 = 0; k0 < N; k0 += 32) {
        __syncthreads();
#pragma unroll
        for (int m = 0; m < 8; ++m) { At[sr][sc + m] = pa[m]; Bt[br][bc + m] = pb[m]; }
        __syncthreads();
        if (k0 + 32 < N) {
            ap += 32; bp += (size_t)32 * N;
#pragma unroll
            for (int m = 0; m < 8; ++m) { pa[m] = ap[m]; pb[m] = bp[m]; }
        }
#pragma unroll
        for (int kk = 0; kk < 32; ++kk) {
            double av[4], bv[4];
#pragma unroll
            for (int p = 0; p < 4; ++p) av[p] = At[ty + 16 * p][kk];
#pragma unroll
            for (int q = 0; q < 4; ++q) bv[q] = Bt[kk][tx + 16 * q];
#pragma unroll
            for (int p = 0; p < 4; ++p)
#pragma unroll
                for (int q = 0; q < 4; ++q)
                    acc[p][q] = fma(av[p], bv[q], acc[p][q]);
        }
    }
#pragma unroll
    for (int p = 0; p < 4; ++p)
#pragma unroll
        for (int q = 0; q < 4; ++q) {
            size_t idx = (size_t)(i0 + ty + 16 * p) * N + (j0 + tx + 16 * q);
            double w = acc[p][q];
            Wb[idx] = w;
            kb[idx] = (unsigned int)(d2key(w) >> 32);
        }
}

// ---------------------------------------------------------------------------
// K4: fp64 row softmax. Wave per row, shuffle-only; grid 512 wgs.
__global__ __launch_bounds__(256) void k_softmax(double* __restrict__ L) {
    int row = (blockIdx.x << 2) + (threadIdx.x >> 6);  // 0..2047
    int ln  = threadIdx.x & 63;
    double* p = L + (size_t)row * N;

    double v[16];
#pragma unroll
    for (int q = 0; q < 16; ++q) v[q] = p[ln + 64 * q];

    double mx = v[0];
#pragma unroll
    for (int q = 1; q < 16; ++q) mx = fmax(mx, v[q]);
#pragma unroll
    for (int off = 32; off >= 1; off >>= 1) mx = fmax(mx, __shfl_xor(mx, off));

    double s = 0.0;
#pragma unroll
    for (int q = 0; q < 16; ++q) { v[q] = exp(v[q] - mx); s += v[q]; }
#pragma unroll
    for (int off = 32; off >= 1; off >>= 1) s += __shfl_xor(s, off);

#pragma unroll
    for (int q = 0; q < 16; ++q) p[ln + 64 * q] = v[q] / s;
}

// ---------------------------------------------------------------------------
// Radix select stage A: 4 passes over key32.
// st[2b] = accumulating threshold prefix, st[2b+1] = remaining k.

__global__ __launch_bounds__(256) void k_sel_init(unsigned long long* st,
                                                  int* __restrict__ hist,
                                                  int* __restrict__ eqbuf,
                                                  unsigned int* __restrict__ sc) {
    int t = threadIdx.x;
    hist[t] = 0; hist[256 + t] = 0;
    if (t < BB) {
        st[2 * t]     = 0ULL;
        st[2 * t + 1] = (unsigned long long)KSEL;
        eqbuf[t * ESTRIDE] = 0;
        sc[2 * t] = 0u; sc[2 * t + 1] = 0u;
    }
}

// 512 blocks x 256 thr; blocks [0,256) -> batch 0, [256,512) -> batch 1.
__global__ __launch_bounds__(256) void k_sel_hist(const unsigned int* __restrict__ key32,
                                                  const unsigned long long* __restrict__ st,
                                                  int* __restrict__ hist, int shift) {
    __shared__ int lh[256];
    int t = threadIdx.x;
    lh[t] = 0;
    __syncthreads();
    int b  = blockIdx.x >> 8;
    int hb = blockIdx.x & 255;
    int hs = shift + 8;
    unsigned long long pref = st[2 * b] >> hs;
    const uint4* k4 = (const uint4*)(key32 + (size_t)b * S);
    int tloc = hb * 256 + t;
#pragma unroll
    for (int it = 0; it < 4; ++it) {
        uint4 kv = k4[tloc + it * 65536];
        unsigned int ks[4] = {kv.x, kv.y, kv.z, kv.w};
#pragma unroll
        for (int c = 0; c < 4; ++c) {
            unsigned long long key = (unsigned long long)ks[c];
            bool match = (shift == 24) || ((key >> hs) == pref);
            if (match) atomicAdd(&lh[(int)((ks[c] >> shift) & 255u)], 1);
        }
    }
    __syncthreads();
    atomicAdd(&hist[b * 256 + t], lh[t]);
}

__global__ __launch_bounds__(256) void k_sel_scan(unsigned long long* st,
                                                  int* __restrict__ hist, int shift) {
    int t = threadIdx.x;
    if (t < BB) {
        unsigned long long kneed = st[2 * t + 1];
        unsigned long long cum = 0;
        int bucket = 0;
        for (int i = 255; i >= 0; --i) {
            unsigned long long h = (unsigned long long)hist[t * 256 + i];
            if (cum + h >= kneed) { bucket = i; break; }
            cum += h;
        }
        st[2 * t]     |= ((unsigned long long)bucket) << shift;
        st[2 * t + 1]  = kneed - cum;
    }
    __syncthreads();
    hist[t] = 0; hist[256 + t] = 0;
}

// Stage B: collect (low32, idx) for key32 == T32. 256 wgs grid-strided.
__global__ __launch_bounds__(256) void k_sel_eq(const unsigned int* __restrict__ key32,
                                                const double* __restrict__ W,
                                                const unsigned long long* __restrict__ st,
                                                int* __restrict__ eqbuf) {
    int tid = blockIdx.x * 256 + threadIdx.x;      // 0..65535
    const uint4* k4 = (const uint4*)key32;
    unsigned int T0 = (unsigned int)st[0];
    unsigned int T1 = (unsigned int)st[2];
#pragma unroll
    for (int it = 0; it < 8; ++it) {
        int idx4 = tid + it * 65536;               // 0..524287
        uint4 kv = k4[idx4];
        int b = idx4 >> 18;
        unsigned int T = b ? T1 : T0;
        int base = (idx4 << 2) & (S - 1);
        unsigned int ks[4] = {kv.x, kv.y, kv.z, kv.w};
#pragma unroll
        for (int c = 0; c < 4; ++c) {
            if (ks[c] == T) {
                int p = atomicAdd(&eqbuf[b * ESTRIDE], 1);
                if (p < EQCAP) {
                    int s = base + c;
                    unsigned int low = (unsigned int)d2key(W[(size_t)b * S + s]);
                    eqbuf[b * ESTRIDE + 1 + 2 * p] = (int)low;
                    eqbuf[b * ESTRIDE + 2 + 2 * p] = s;
                }
            }
        }
    }
}

// Stage C: exact refinement. One block per batch. 4 radix passes on low32,
// then 3 radix passes on the (unique) flat index -> (TL, sCut).
__global__ __launch_bounds__(256) void k_sel_refine(const unsigned long long* __restrict__ st,
                                                    const int* __restrict__ eqbuf,
                                                    unsigned int* __restrict__ sc) {
    int b = blockIdx.x;
    int t = threadIdx.x;
    const int* eb = eqbuf + b * ESTRIDE;
    int cnt = eb[0];
    if (cnt > EQCAP) cnt = EQCAP;

    __shared__ int hist[256];
    __shared__ unsigned int sh_pref;
    __shared__ unsigned long long sh_kneed;
    if (t == 0) { sh_pref = 0u; sh_kneed = st[2 * b + 1]; }
    __syncthreads();

    // --- low32 select (4 passes, msb first)
    for (int shift = 24; shift >= 0; shift -= 8) {
        hist[t] = 0;
        __syncthreads();
        unsigned int pref = sh_pref;
        for (int e = t; e < cnt; e += 256) {
            unsigned int low = (unsigned int)eb[1 + 2 * e];
            bool match = (shift == 24) || (((low ^ pref) >> (shift + 8)) == 0u);
            if (match) atomicAdd(&hist[(low >> shift) & 255u], 1);
        }
        __syncthreads();
        if (t == 0) {
            unsigned long long kneed = sh_kneed, cum = 0;
            int bucket = 0;
            for (int i = 255; i >= 0; --i) {
                unsigned long long h = (unsigned long long)hist[i];
                if (cum + h >= kneed) { bucket = i; break; }
                cum += h;
            }
            sh_pref  = pref | ((unsigned int)bucket << shift);
            sh_kneed = kneed - cum;
        }
        __syncthreads();
    }
    unsigned int TL = sh_pref;
    __syncthreads();
    if (t == 0) sh_pref = 0u;
    __syncthreads();

    // --- index select among full-key ties (3 passes; indices < 2^20, unique)
    for (int shift = 16; shift >= 0; shift -= 8) {
        hist[t] = 0;
        __syncthreads();
        unsigned int pref = sh_pref;
        for (int e = t; e < cnt; e += 256) {
            unsigned int low = (unsigned int)eb[1 + 2 * e];
            if (low != TL) continue;
            unsigned int idx = (unsigned int)eb[2 + 2 * e];
            bool match = (shift == 16) || (((idx ^ pref) >> (shift + 8)) == 0u);
            if (match) atomicAdd(&hist[(idx >> shift) & 255u], 1);
        }
        __syncthreads();
        if (t == 0) {
            unsigned long long kneed = sh_kneed, cum = 0;
            int bucket = 0;
            for (int i = 255; i >= 0; --i) {
                unsigned long long h = (unsigned long long)hist[i];
                if (cum + h >= kneed) { bucket = i; break; }
                cum += h;
            }
            sh_pref  = pref | ((unsigned int)bucket << shift);
            sh_kneed = kneed - cum;
        }
        __syncthreads();
    }
    if (t == 0) {
        sc[2 * b]     = TL;       // low32 threshold
        sc[2 * b + 1] = sh_pref;  // exact index cutoff: selected iff idx >= sCut
    }
}

// Final mask: pure streaming, no loops. 256 wgs.
__global__ __launch_bounds__(256) void k_sel_mask(const unsigned int* __restrict__ key32,
                                                  const double* __restrict__ W,
                                                  const unsigned long long* __restrict__ st,
                                                  const unsigned int* __restrict__ sc,
                                                  float* __restrict__ out) {
    int tid = blockIdx.x * 256 + threadIdx.x;      // 0..65535
    const uint4* k4 = (const uint4*)key32;
    float4* out4 = (float4*)out;
    unsigned int T0 = (unsigned int)st[0];
    unsigned int T1 = (unsigned int)st[2];
#pragma unroll
    for (int it = 0; it < 8; ++it) {
        int idx4 = tid + it * 65536;
        uint4 kv = k4[idx4];
        int b = idx4 >> 18;
        unsigned int T    = b ? T1 : T0;
        unsigned int TL   = sc[2 * b];
        unsigned int sCut = sc[2 * b + 1];
        int base = (idx4 << 2) & (S - 1);
        unsigned int ks[4] = {kv.x, kv.y, kv.z, kv.w};
        float ov[4];
#pragma unroll
        for (int c = 0; c < 4; ++c) {
            float v = 0.0f;
            if (ks[c] > T) {
                v = 1.0f;
            } else if (ks[c] == T) {
                int s = base + c;
                unsigned int low = (unsigned int)d2key(W[(size_t)b * S + s]);
                v = (low > TL || (low == TL && (unsigned int)s >= sCut)) ? 1.0f : 0.0f;
            }
            ov[c] = v;
        }
        out4[idx4] = make_float4(ov[0], ov[1], ov[2], ov[3]);
    }
}

// ---------------------------------------------------------------------------
extern "C" void kernel_launch(void* const* d_in, const int* in_sizes, int n_in,
                              void* d_out, int out_size, void* d_ws, size_t ws_size,
                              hipStream_t stream) {
    const float* x = (const float*)d_in[0];
    float* out = (float*)d_out;

    char* ws = (char*)d_ws;
    size_t off = 0;
    auto alloc = [&](size_t bytes) -> void* {
        void* p = ws + off;
        off += (bytes + 255) & ~(size_t)255;
        return p;
    };

    double* xd    = (double*)alloc((size_t)BB * N * C * sizeof(double));
    double* mean  = (double*)alloc((size_t)BB * N * sizeof(double));
    double* rr    = (double*)alloc((size_t)BB * N * sizeof(double));
    double* sinv  = (double*)alloc((size_t)BB * N * sizeof(double));
    double* E     = (double*)alloc((size_t)BB * S * sizeof(double));       // 16 MB
    double* Ch    = (double*)alloc((size_t)BB * S * sizeof(double));       // 16 MB
    double* Cc    = (double*)alloc((size_t)BB * S * sizeof(double));       // 16 MB
    double* L     = (double*)alloc((size_t)BB * S * sizeof(double));       // 16 MB
    unsigned int* key32 = (unsigned int*)alloc((size_t)BB * S * sizeof(unsigned int)); // 8 MB
    double* W     = E;  // E dead after gemm_nt -> reuse for weighted
    unsigned long long* st = (unsigned long long*)alloc(64);
    unsigned int* sc = (unsigned int*)alloc(64);
    int* hist  = (int*)alloc((size_t)BB * 256 * sizeof(int));
    int* eqbuf = (int*)alloc((size_t)BB * ESTRIDE * sizeof(int));          // ~1 MB

    // 1) per-row stats + fp64 upconvert
    k_prep<<<32, 256, 0, stream>>>(x, xd, mean, rr, sinv);

    // 2) pairwise adjacencies (64x64 tiles, 512 wgs)
    k_pairwise<<<dim3(N / 64, N / 64, BB), 256, 0, stream>>>(xd, mean, rr, sinv, E, Ch, Cc);

    // 3) logits = (E @ Ch^T) * 1/8   (64x64 tiles -> 512 wgs, 2 blocks/CU)
    k_gemm_nt<<<dim3(N / 64, N / 64, BB), 256, 0, stream>>>(E, Ch, L, 0.125);

    // 4) softmax rows (wave per row, 512 wgs)
    k_softmax<<<512, 256, 0, stream>>>(L);

    // 5) weighted = attn @ Cc (into W == E) + fused key32 epilogue
    k_gemm_nn<<<dim3(N / 64, N / 64, BB), 256, 0, stream>>>(L, Cc, W, key32);

    // 6) stage A: 4-pass radix select on key32
    k_sel_init<<<1, 256, 0, stream>>>(st, hist, eqbuf, sc);
    for (int pass = 0; pass < 4; ++pass) {
        int shift = 24 - 8 * pass;
        k_sel_hist<<<512, 256, 0, stream>>>(key32, st, hist, shift);
        k_sel_scan<<<1, 256, 0, stream>>>(st, hist, shift);
    }

    // 7) stage B+C: exact tie refinement (no per-thread loops anywhere)
    k_sel_eq<<<256, 256, 0, stream>>>(key32, W, st, eqbuf);
    k_sel_refine<<<BB, 256, 0, stream>>>(st, eqbuf, sc);

    // 8) final mask (pure streaming)
    k_sel_mask<<<256, 256, 0, stream>>>(key32, W, st, sc, out);
}

// Round 5
// 452.253 us; speedup vs baseline: 3.4699x; 1.2910x over previous
//
#include <hip/hip_runtime.h>
#include <hip/hip_bf16.h>

// Problem constants (from setup_inputs: x = [2, 1024, 64] fp32)
constexpr int BB = 2;
constexpr int N  = 1024;
constexpr int C  = 64;
constexpr int S  = N * N;          // 1048576 = 2^20
constexpr int KSEL = S / 6;        // 174762 entries set to 1 per batch
constexpr int EQCAP   = 65536;     // tie-list capacity per batch (exact dup rows!)
constexpr int ESTRIDE = 1 + 2 * EQCAP;

typedef double d4 __attribute__((ext_vector_type(4)));

// Order-preserving uint64 mapping of fp64 (monotone: a<b <=> key(a)<key(b))
__device__ __forceinline__ unsigned long long d2key(double d) {
    unsigned long long u = (unsigned long long)__double_as_longlong(d);
    return (u & 0x8000000000000000ULL) ? ~u : (u | 0x8000000000000000ULL);
}

// ---------------------------------------------------------------------------
// K1: per-row prep. Wave per row, grid-strided (32 wgs; dispatch-rate safe).
__global__ __launch_bounds__(256) void k_prep(const float* __restrict__ x,
                                              double* __restrict__ xd,
                                              double* __restrict__ mean,
                                              double* __restrict__ rr,
                                              double* __restrict__ sinv) {
    int wv = (blockIdx.x << 2) + (threadIdx.x >> 6);   // 0..127
    int c  = threadIdx.x & 63;
    for (int row = wv; row < BB * N; row += 128) {
        double v = (double)x[row * C + c];

        double s = v;
#pragma unroll
        for (int off = 32; off >= 1; off >>= 1) s += __shfl_xor(s, off);
        double m = s / 64.0;

        double w = v - m;
        double q = w * w;
#pragma unroll
        for (int off = 32; off >= 1; off >>= 1) q += __shfl_xor(q, off);

        double r = v * v;
#pragma unroll
        for (int off = 32; off >= 1; off >>= 1) r += __shfl_xor(r, off);

        xd[row * C + c] = v;
        if (c == 0) {
            mean[row] = m;
            rr[row]   = r;
            sinv[row] = 1.0 / sqrt(q);
        }
    }
}

// ---------------------------------------------------------------------------
// K2: pairwise adjacencies, 64x64 tile per wg (512 wgs), 4x4 pairs/thread.
__global__ __launch_bounds__(256) void k_pairwise(const double* __restrict__ xd,
                                                  const double* __restrict__ mean,
                                                  const double* __restrict__ rr,
                                                  const double* __restrict__ sinv,
                                                  double* __restrict__ E,
                                                  double* __restrict__ Ch,
                                                  double* __restrict__ Cc) {
    int b  = blockIdx.z;
    int i0 = blockIdx.y * 64;
    int j0 = blockIdx.x * 64;
    __shared__ double xi[64][65];
    __shared__ double xj[64][65];

    int t  = threadIdx.x;
    int r  = t >> 2;
    int cb = (t & 3) * 16;
    const double* xb = xd + (size_t)b * N * C;
    {
        const double* pi = xb + (size_t)(i0 + r) * C + cb;
        const double* pj = xb + (size_t)(j0 + r) * C + cb;
#pragma unroll
        for (int m = 0; m < 16; ++m) { xi[r][cb + m] = pi[m]; xj[r][cb + m] = pj[m]; }
    }
    __syncthreads();

    int ty = t >> 4, tx = t & 15;
    double adot[4][4] = {};
    double amax[4][4] = {};
#pragma unroll 8
    for (int c = 0; c < 64; ++c) {
        double ai[4], aj[4];
#pragma unroll
        for (int p = 0; p < 4; ++p) ai[p] = xi[ty + 16 * p][c];
#pragma unroll
        for (int q = 0; q < 4; ++q) aj[q] = xj[tx + 16 * q][c];
#pragma unroll
        for (int p = 0; p < 4; ++p)
#pragma unroll
            for (int q = 0; q < 4; ++q) {
                double d = ai[p] - aj[q];
                amax[p][q] = fmax(amax[p][q], fabs(d));
                adot[p][q] = fma(ai[p], aj[q], adot[p][q]);
            }
    }

#pragma unroll
    for (int p = 0; p < 4; ++p) {
        int ii = i0 + ty + 16 * p;
        int gi = b * N + ii;
        double rri = rr[gi], mi = mean[gi], si = sinv[gi];
#pragma unroll
        for (int q = 0; q < 4; ++q) {
            int jj = j0 + tx + 16 * q;
            int gj = b * N + jj;
            double dot = adot[p][q];
            double d2  = rri + rr[gj] - 2.0 * dot;
            double e   = (ii == jj) ? 0.0 : sqrt(fmax(d2, 0.0));
            double cc  = (dot - 64.0 * mi * mean[gj]) * si * sinv[gj];
            cc = fmin(1.0, fmax(-1.0, cc));
            size_t idx = (size_t)b * S + (size_t)ii * N + jj;
            E[idx]  = e;
            Ch[idx] = amax[p][q];
            Cc[idx] = cc;
        }
    }
}

// ---------------------------------------------------------------------------
// K3: C = scale * A * B^T (fp64, MFMA). 64x64 tile/block (512 wgs, 2/CU),
// 4 waves x 32x32 quadrant, v_mfma_f64_16x16x4, BK=32, reg double-buffer.
__global__ __launch_bounds__(256) void k_gemm_nt(const double* __restrict__ A,
                                                 const double* __restrict__ Bm,
                                                 double* __restrict__ Cm,
                                                 double scale) {
    int b = blockIdx.z;
    const double* Ab = A  + (size_t)b * S;
    const double* Bb = Bm + (size_t)b * S;
    double*       Cb = Cm + (size_t)b * S;
    int i0 = blockIdx.y * 64, j0 = blockIdx.x * 64;

    __shared__ double At[64][33];
    __shared__ double Bt[64][33];

    int t    = threadIdx.x;
    int lane = t & 63;
    int w    = t >> 6;
    int wr   = (w >> 1) * 32;      // quadrant row offset in tile
    int wc   = (w & 1) * 32;       // quadrant col offset in tile
    int fm   = lane & 15;          // frag m/n index
    int fk   = lane >> 4;          // frag k index (0..3)

    int sr = t >> 2, sc = (t & 3) * 8;   // staging: 64 rows x 32 k

    d4 acc00 = {0.0, 0.0, 0.0, 0.0};
    d4 acc01 = acc00, acc10 = acc00, acc11 = acc00;

    const double* ap = Ab + (size_t)(i0 + sr) * N + sc;
    const double* bp = Bb + (size_t)(j0 + sr) * N + sc;

    double pa[8], pb[8];
#pragma unroll
    for (int m = 0; m < 8; ++m) { pa[m] = ap[m]; pb[m] = bp[m]; }

    for (int k0 = 0; k0 < N; k0 += 32) {
        __syncthreads();
#pragma unroll
        for (int m = 0; m < 8; ++m) { At[sr][sc + m] = pa[m]; Bt[sr][sc + m] = pb[m]; }
        __syncthreads();
        if (k0 + 32 < N) {
            ap += 32; bp += 32;
#pragma unroll
            for (int m = 0; m < 8; ++m) { pa[m] = ap[m]; pb[m] = bp[m]; }
        }
#pragma unroll
        for (int kq = 0; kq < 8; ++kq) {
            int kk = kq * 4 + fk;
            double a0 = At[wr + fm][kk];
            double a1 = At[wr + 16 + fm][kk];
            double b0 = Bt[wc + fm][kk];
            double b1 = Bt[wc + 16 + fm][kk];
            acc00 = __builtin_amdgcn_mfma_f64_16x16x4f64(a0, b0, acc00, 0, 0, 0);
            acc01 = __builtin_amdgcn_mfma_f64_16x16x4f64(a0, b1, acc01, 0, 0, 0);
            acc10 = __builtin_amdgcn_mfma_f64_16x16x4f64(a1, b0, acc10, 0, 0, 0);
            acc11 = __builtin_amdgcn_mfma_f64_16x16x4f64(a1, b1, acc11, 0, 0, 0);
        }
    }
    // D layout: row = 4*fk + reg, col = fm (within each 16x16 tile)
    int r0 = i0 + wr + 4 * fk;
    int c0 = j0 + wc + fm;
#pragma unroll
    for (int r = 0; r < 4; ++r) {
        Cb[(size_t)(r0 + r)      * N + c0]      = acc00[r] * scale;
        Cb[(size_t)(r0 + r)      * N + c0 + 16] = acc01[r] * scale;
        Cb[(size_t)(r0 + 16 + r) * N + c0]      = acc10[r] * scale;
        Cb[(size_t)(r0 + 16 + r) * N + c0 + 16] = acc11[r] * scale;
    }
}

// ---------------------------------------------------------------------------
// K5: W = A * B (fp64, MFMA) + fused key32 epilogue. Same blocking as K3.
__global__ __launch_bounds__(256) void k_gemm_nn(const double* __restrict__ A,
                                                 const double* __restrict__ Bm,
                                                 double* __restrict__ Wm,
                                                 unsigned int* __restrict__ kq_out) {
    int b = blockIdx.z;
    const double* Ab = A  + (size_t)b * S;
    const double* Bb = Bm + (size_t)b * S;
    double*       Wb = Wm + (size_t)b * S;
    unsigned int* kb = kq_out + (size_t)b * S;
    int i0 = blockIdx.y * 64, j0 = blockIdx.x * 64;

    __shared__ double At[64][33];
    __shared__ double Bt[32][65];

    int t    = threadIdx.x;
    int lane = t & 63;
    int w    = t >> 6;
    int wr   = (w >> 1) * 32;
    int wc   = (w & 1) * 32;
    int fm   = lane & 15;
    int fk   = lane >> 4;

    int sr = t >> 2, sc = (t & 3) * 8;   // A staging: 64 rows x 32 k
    int br = t >> 3, bc = (t & 7) * 8;   // B staging: 32 k x 64 cols

    d4 acc00 = {0.0, 0.0, 0.0, 0.0};
    d4 acc01 = acc00, acc10 = acc00, acc11 = acc00;

    const double* ap = Ab + (size_t)(i0 + sr) * N + sc;
    const double* bp = Bb + (size_t)br * N + j0 + bc;

    double pa[8], pb[8];
#pragma unroll
    for (int m = 0; m < 8; ++m) { pa[m] = ap[m]; pb[m] = bp[m]; }

    for (int k0 = 0; k0 < N; k0 += 32) {
        __syncthreads();
#pragma unroll
        for (int m = 0; m < 8; ++m) { At[sr][sc + m] = pa[m]; Bt[br][bc + m] = pb[m]; }
        __syncthreads();
        if (k0 + 32 < N) {
            ap += 32; bp += (size_t)32 * N;
#pragma unroll
            for (int m = 0; m < 8; ++m) { pa[m] = ap[m]; pb[m] = bp[m]; }
        }
#pragma unroll
        for (int kq = 0; kq < 8; ++kq) {
            int kk = kq * 4 + fk;
            double a0 = At[wr + fm][kk];
            double a1 = At[wr + 16 + fm][kk];
            double b0 = Bt[kk][wc + fm];
            double b1 = Bt[kk][wc + 16 + fm];
            acc00 = __builtin_amdgcn_mfma_f64_16x16x4f64(a0, b0, acc00, 0, 0, 0);
            acc01 = __builtin_amdgcn_mfma_f64_16x16x4f64(a0, b1, acc01, 0, 0, 0);
            acc10 = __builtin_amdgcn_mfma_f64_16x16x4f64(a1, b0, acc10, 0, 0, 0);
            acc11 = __builtin_amdgcn_mfma_f64_16x16x4f64(a1, b1, acc11, 0, 0, 0);
        }
    }
    int r0 = i0 + wr + 4 * fk;
    int c0 = j0 + wc + fm;
#pragma unroll
    for (int r = 0; r < 4; ++r) {
        double w00 = acc00[r], w01 = acc01[r], w10 = acc10[r], w11 = acc11[r];
        size_t i00 = (size_t)(r0 + r)      * N + c0;
        size_t i01 = (size_t)(r0 + r)      * N + c0 + 16;
        size_t i10 = (size_t)(r0 + 16 + r) * N + c0;
        size_t i11 = (size_t)(r0 + 16 + r) * N + c0 + 16;
        Wb[i00] = w00; kb[i00] = (unsigned int)(d2key(w00) >> 32);
        Wb[i01] = w01; kb[i01] = (unsigned int)(d2key(w01) >> 32);
        Wb[i10] = w10; kb[i10] = (unsigned int)(d2key(w10) >> 32);
        Wb[i11] = w11; kb[i11] = (unsigned int)(d2key(w11) >> 32);
    }
}

// ---------------------------------------------------------------------------
// K4: fp64 row softmax. Wave per row, shuffle-only; grid 512 wgs.
__global__ __launch_bounds__(256) void k_softmax(double* __restrict__ L) {
    int row = (blockIdx.x << 2) + (threadIdx.x >> 6);  // 0..2047
    int ln  = threadIdx.x & 63;
    double* p = L + (size_t)row * N;

    double v[16];
#pragma unroll
    for (int q = 0; q < 16; ++q) v[q] = p[ln + 64 * q];

    double mx = v[0];
#pragma unroll
    for (int q = 1; q < 16; ++q) mx = fmax(mx, v[q]);
#pragma unroll
    for (int off = 32; off >= 1; off >>= 1) mx = fmax(mx, __shfl_xor(mx, off));

    double s = 0.0;
#pragma unroll
    for (int q = 0; q < 16; ++q) { v[q] = exp(v[q] - mx); s += v[q]; }
#pragma unroll
    for (int off = 32; off >= 1; off >>= 1) s += __shfl_xor(s, off);

#pragma unroll
    for (int q = 0; q < 16; ++q) p[ln + 64 * q] = v[q] / s;
}

// ---------------------------------------------------------------------------
// Radix select stage A: 4 passes over key32.
// st[2b] = accumulating threshold prefix, st[2b+1] = remaining k.

__global__ __launch_bounds__(256) void k_sel_init(unsigned long long* st,
                                                  int* __restrict__ hist,
                                                  int* __restrict__ eqbuf,
                                                  unsigned int* __restrict__ sc) {
    int t = threadIdx.x;
    hist[t] = 0; hist[256 + t] = 0;
    if (t < BB) {
        st[2 * t]     = 0ULL;
        st[2 * t + 1] = (unsigned long long)KSEL;
        eqbuf[t * ESTRIDE] = 0;
        sc[2 * t] = 0u; sc[2 * t + 1] = 0u;
    }
}

// 512 blocks x 256 thr; blocks [0,256) -> batch 0, [256,512) -> batch 1.
__global__ __launch_bounds__(256) void k_sel_hist(const unsigned int* __restrict__ key32,
                                                  const unsigned long long* __restrict__ st,
                                                  int* __restrict__ hist, int shift) {
    __shared__ int lh[256];
    int t = threadIdx.x;
    lh[t] = 0;
    __syncthreads();
    int b  = blockIdx.x >> 8;
    int hb = blockIdx.x & 255;
    int hs = shift + 8;
    unsigned long long pref = st[2 * b] >> hs;
    const uint4* k4 = (const uint4*)(key32 + (size_t)b * S);
    int tloc = hb * 256 + t;
#pragma unroll
    for (int it = 0; it < 4; ++it) {
        uint4 kv = k4[tloc + it * 65536];
        unsigned int ks[4] = {kv.x, kv.y, kv.z, kv.w};
#pragma unroll
        for (int c = 0; c < 4; ++c) {
            unsigned long long key = (unsigned long long)ks[c];
            bool match = (shift == 24) || ((key >> hs) == pref);
            if (match) atomicAdd(&lh[(int)((ks[c] >> shift) & 255u)], 1);
        }
    }
    __syncthreads();
    atomicAdd(&hist[b * 256 + t], lh[t]);
}

__global__ __launch_bounds__(256) void k_sel_scan(unsigned long long* st,
                                                  int* __restrict__ hist, int shift) {
    int t = threadIdx.x;
    if (t < BB) {
        unsigned long long kneed = st[2 * t + 1];
        unsigned long long cum = 0;
        int bucket = 0;
        for (int i = 255; i >= 0; --i) {
            unsigned long long h = (unsigned long long)hist[t * 256 + i];
            if (cum + h >= kneed) { bucket = i; break; }
            cum += h;
        }
        st[2 * t]     |= ((unsigned long long)bucket) << shift;
        st[2 * t + 1]  = kneed - cum;
    }
    __syncthreads();
    hist[t] = 0; hist[256 + t] = 0;
}

// Stage B: collect (low32, idx) for key32 == T32. 256 wgs grid-strided.
__global__ __launch_bounds__(256) void k_sel_eq(const unsigned int* __restrict__ key32,
                                                const double* __restrict__ W,
                                                const unsigned long long* __restrict__ st,
                                                int* __restrict__ eqbuf) {
    int tid = blockIdx.x * 256 + threadIdx.x;      // 0..65535
    const uint4* k4 = (const uint4*)key32;
    unsigned int T0 = (unsigned int)st[0];
    unsigned int T1 = (unsigned int)st[2];
#pragma unroll
    for (int it = 0; it < 8; ++it) {
        int idx4 = tid + it * 65536;               // 0..524287
        uint4 kv = k4[idx4];
        int b = idx4 >> 18;
        unsigned int T = b ? T1 : T0;
        int base = (idx4 << 2) & (S - 1);
        unsigned int ks[4] = {kv.x, kv.y, kv.z, kv.w};
#pragma unroll
        for (int c = 0; c < 4; ++c) {
            if (ks[c] == T) {
                int p = atomicAdd(&eqbuf[b * ESTRIDE], 1);
                if (p < EQCAP) {
                    int s = base + c;
                    unsigned int low = (unsigned int)d2key(W[(size_t)b * S + s]);
                    eqbuf[b * ESTRIDE + 1 + 2 * p] = (int)low;
                    eqbuf[b * ESTRIDE + 2 + 2 * p] = s;
                }
            }
        }
    }
}

// Stage C: exact refinement. One block per batch. 4 radix passes on low32,
// then 3 radix passes on the (unique) flat index -> (TL, sCut).
__global__ __launch_bounds__(256) void k_sel_refine(const unsigned long long* __restrict__ st,
                                                    const int* __restrict__ eqbuf,
                                                    unsigned int* __restrict__ sc) {
    int b = blockIdx.x;
    int t = threadIdx.x;
    const int* eb = eqbuf + b * ESTRIDE;
    int cnt = eb[0];
    if (cnt > EQCAP) cnt = EQCAP;

    __shared__ int hist[256];
    __shared__ unsigned int sh_pref;
    __shared__ unsigned long long sh_kneed;
    if (t == 0) { sh_pref = 0u; sh_kneed = st[2 * b + 1]; }
    __syncthreads();

    // --- low32 select (4 passes, msb first)
    for (int shift = 24; shift >= 0; shift -= 8) {
        hist[t] = 0;
        __syncthreads();
        unsigned int pref = sh_pref;
        for (int e = t; e < cnt; e += 256) {
            unsigned int low = (unsigned int)eb[1 + 2 * e];
            bool match = (shift == 24) || (((low ^ pref) >> (shift + 8)) == 0u);
            if (match) atomicAdd(&hist[(low >> shift) & 255u], 1);
        }
        __syncthreads();
        if (t == 0) {
            unsigned long long kneed = sh_kneed, cum = 0;
            int bucket = 0;
            for (int i = 255; i >= 0; --i) {
                unsigned long long h = (unsigned long long)hist[i];
                if (cum + h >= kneed) { bucket = i; break; }
                cum += h;
            }
            sh_pref  = pref | ((unsigned int)bucket << shift);
            sh_kneed = kneed - cum;
        }
        __syncthreads();
    }
    unsigned int TL = sh_pref;
    __syncthreads();
    if (t == 0) sh_pref = 0u;
    __syncthreads();

    // --- index select among full-key ties (3 passes; indices < 2^20, unique)
    for (int shift = 16; shift >= 0; shift -= 8) {
        hist[t] = 0;
        __syncthreads();
        unsigned int pref = sh_pref;
        for (int e = t; e < cnt; e += 256) {
            unsigned int low = (unsigned int)eb[1 + 2 * e];
            if (low != TL) continue;
            unsigned int idx = (unsigned int)eb[2 + 2 * e];
            bool match = (shift == 16) || (((idx ^ pref) >> (shift + 8)) == 0u);
            if (match) atomicAdd(&hist[(idx >> shift) & 255u], 1);
        }
        __syncthreads();
        if (t == 0) {
            unsigned long long kneed = sh_kneed, cum = 0;
            int bucket = 0;
            for (int i = 255; i >= 0; --i) {
                unsigned long long h = (unsigned long long)hist[i];
                if (cum + h >= kneed) { bucket = i; break; }
                cum += h;
            }
            sh_pref  = pref | ((unsigned int)bucket << shift);
            sh_kneed = kneed - cum;
        }
        __syncthreads();
    }
    if (t == 0) {
        sc[2 * b]     = TL;       // low32 threshold
        sc[2 * b + 1] = sh_pref;  // exact index cutoff: selected iff idx >= sCut
    }
}

// Final mask: pure streaming, no loops. 256 wgs.
__global__ __launch_bounds__(256) void k_sel_mask(const unsigned int* __restrict__ key32,
                                                  const double* __restrict__ W,
                                                  const unsigned long long* __restrict__ st,
                                                  const unsigned int* __restrict__ sc,
                                                  float* __restrict__ out) {
    int tid = blockIdx.x * 256 + threadIdx.x;      // 0..65535
    const uint4* k4 = (const uint4*)key32;
    float4* out4 = (float4*)out;
    unsigned int T0 = (unsigned int)st[0];
    unsigned int T1 = (unsigned int)st[2];
#pragma unroll
    for (int it = 0; it < 8; ++it) {
        int idx4 = tid + it * 65536;
        uint4 kv = k4[idx4];
        int b = idx4 >> 18;
        unsigned int T    = b ? T1 : T0;
        unsigned int TL   = sc[2 * b];
        unsigned int sCut = sc[2 * b + 1];
        int base = (idx4 << 2) & (S - 1);
        unsigned int ks[4] = {kv.x, kv.y, kv.z, kv.w};
        float ov[4];
#pragma unroll
        for (int c = 0; c < 4; ++c) {
            float v = 0.0f;
            if (ks[c] > T) {
                v = 1.0f;
            } else if (ks[c] == T) {
                int s = base + c;
                unsigned int low = (unsigned int)d2key(W[(size_t)b * S + s]);
                v = (low > TL || (low == TL && (unsigned int)s >= sCut)) ? 1.0f : 0.0f;
            }
            ov[c] = v;
        }
        out4[idx4] = make_float4(ov[0], ov[1], ov[2], ov[3]);
    }
}

// ---------------------------------------------------------------------------
extern "C" void kernel_launch(void* const* d_in, const int* in_sizes, int n_in,
                              void* d_out, int out_size, void* d_ws, size_t ws_size,
                              hipStream_t stream) {
    const float* x = (const float*)d_in[0];
    float* out = (float*)d_out;

    char* ws = (char*)d_ws;
    size_t off = 0;
    auto alloc = [&](size_t bytes) -> void* {
        void* p = ws + off;
        off += (bytes + 255) & ~(size_t)255;
        return p;
    };

    double* xd    = (double*)alloc((size_t)BB * N * C * sizeof(double));
    double* mean  = (double*)alloc((size_t)BB * N * sizeof(double));
    double* rr    = (double*)alloc((size_t)BB * N * sizeof(double));
    double* sinv  = (double*)alloc((size_t)BB * N * sizeof(double));
    double* E     = (double*)alloc((size_t)BB * S * sizeof(double));       // 16 MB
    double* Ch    = (double*)alloc((size_t)BB * S * sizeof(double));       // 16 MB
    double* Cc    = (double*)alloc((size_t)BB * S * sizeof(double));       // 16 MB
    double* L     = (double*)alloc((size_t)BB * S * sizeof(double));       // 16 MB
    unsigned int* key32 = (unsigned int*)alloc((size_t)BB * S * sizeof(unsigned int)); // 8 MB
    double* W     = E;  // E dead after gemm_nt -> reuse for weighted
    unsigned long long* st = (unsigned long long*)alloc(64);
    unsigned int* sc = (unsigned int*)alloc(64);
    int* hist  = (int*)alloc((size_t)BB * 256 * sizeof(int));
    int* eqbuf = (int*)alloc((size_t)BB * ESTRIDE * sizeof(int));          // ~1 MB

    // 1) per-row stats + fp64 upconvert
    k_prep<<<32, 256, 0, stream>>>(x, xd, mean, rr, sinv);

    // 2) pairwise adjacencies (64x64 tiles, 512 wgs)
    k_pairwise<<<dim3(N / 64, N / 64, BB), 256, 0, stream>>>(xd, mean, rr, sinv, E, Ch, Cc);

    // 3) logits = (E @ Ch^T) * 1/8   (MFMA f64, 512 wgs)
    k_gemm_nt<<<dim3(N / 64, N / 64, BB), 256, 0, stream>>>(E, Ch, L, 0.125);

    // 4) softmax rows (wave per row, 512 wgs)
    k_softmax<<<512, 256, 0, stream>>>(L);

    // 5) weighted = attn @ Cc (into W == E) + fused key32 epilogue (MFMA f64)
    k_gemm_nn<<<dim3(N / 64, N / 64, BB), 256, 0, stream>>>(L, Cc, W, key32);

    // 6) stage A: 4-pass radix select on key32
    k_sel_init<<<1, 256, 0, stream>>>(st, hist, eqbuf, sc);
    for (int pass = 0; pass < 4; ++pass) {
        int shift = 24 - 8 * pass;
        k_sel_hist<<<512, 256, 0, stream>>>(key32, st, hist, shift);
        k_sel_scan<<<1, 256, 0, stream>>>(st, hist, shift);
    }

    // 7) stage B+C: exact tie refinement (no per-thread loops anywhere)
    k_sel_eq<<<256, 256, 0, stream>>>(key32, W, st, eqbuf);
    k_sel_refine<<<BB, 256, 0, stream>>>(st, eqbuf, sc);

    // 8) final mask (pure streaming)
    k_sel_mask<<<256, 256, 0, stream>>>(key32, W, st, sc, out);
}

// Round 6
// 449.742 us; speedup vs baseline: 3.4893x; 1.0056x over previous
//
#include <hip/hip_runtime.h>
#include <hip/hip_bf16.h>

// Problem constants (from setup_inputs: x = [2, 1024, 64] fp32)
constexpr int BB = 2;
constexpr int N  = 1024;
constexpr int C  = 64;
constexpr int S  = N * N;          // 1048576 = 2^20
constexpr int KSEL = S / 6;        // 174762 entries set to 1 per batch
constexpr int EQCAP   = 65536;     // tie-list capacity per batch (exact dup rows!)
constexpr int ESTRIDE = 1 + 2 * EQCAP;
constexpr int NSELBLK = 256;       // select grid == #CUs -> guaranteed co-resident

typedef double d4 __attribute__((ext_vector_type(4)));

// Order-preserving uint64 mapping of fp64 (monotone: a<b <=> key(a)<key(b))
__device__ __forceinline__ unsigned long long d2key(double d) {
    unsigned long long u = (unsigned long long)__double_as_longlong(d);
    return (u & 0x8000000000000000ULL) ? ~u : (u | 0x8000000000000000ULL);
}

// ---------------------------------------------------------------------------
// K1: pairwise adjacencies with FUSED per-row stats (no separate prep pass).
// 64x64 tile per wg (512 wgs), 4x4 pairs/thread.
__global__ __launch_bounds__(256) void k_pairwise(const float* __restrict__ x,
                                                  double* __restrict__ E,
                                                  double* __restrict__ Ch,
                                                  double* __restrict__ Cc) {
    int b  = blockIdx.z;
    int i0 = blockIdx.y * 64;
    int j0 = blockIdx.x * 64;
    __shared__ double xi[64][65];
    __shared__ double xj[64][65];
    __shared__ double mi[64], ri_[64], si[64];
    __shared__ double mj[64], rj_[64], sj[64];

    int t  = threadIdx.x;
    int r  = t >> 2;
    int cb = (t & 3) * 16;
    const float* xb = x + (size_t)b * N * C;
    {
        const float4* pi = (const float4*)(xb + (size_t)(i0 + r) * C + cb);
        const float4* pj = (const float4*)(xb + (size_t)(j0 + r) * C + cb);
#pragma unroll
        for (int m4 = 0; m4 < 4; ++m4) {
            float4 fi = pi[m4], fj = pj[m4];
            xi[r][cb + 4 * m4 + 0] = (double)fi.x; xi[r][cb + 4 * m4 + 1] = (double)fi.y;
            xi[r][cb + 4 * m4 + 2] = (double)fi.z; xi[r][cb + 4 * m4 + 3] = (double)fi.w;
            xj[r][cb + 4 * m4 + 0] = (double)fj.x; xj[r][cb + 4 * m4 + 1] = (double)fj.y;
            xj[r][cb + 4 * m4 + 2] = (double)fj.z; xj[r][cb + 4 * m4 + 3] = (double)fj.w;
        }
    }
    __syncthreads();

    // per-row stats (serial per row; deterministic -> identical across blocks)
    if (t < 128) {
        int row = t & 63;
        const double (*xs)[65] = (t < 64) ? xi : xj;
        double sum = 0.0, rr = 0.0;
#pragma unroll 8
        for (int c = 0; c < 64; ++c) { double v = xs[row][c]; sum += v; rr = fma(v, v, rr); }
        double m = sum / 64.0;
        double q = 0.0;
#pragma unroll 8
        for (int c = 0; c < 64; ++c) { double w = xs[row][c] - m; q = fma(w, w, q); }
        double sv = 1.0 / sqrt(q);
        if (t < 64) { mi[row] = m; ri_[row] = rr; si[row] = sv; }
        else        { mj[row] = m; rj_[row] = rr; sj[row] = sv; }
    }
    __syncthreads();

    int ty = t >> 4, tx = t & 15;
    double adot[4][4] = {};
    double amax[4][4] = {};
#pragma unroll 8
    for (int c = 0; c < 64; ++c) {
        double ai[4], aj[4];
#pragma unroll
        for (int p = 0; p < 4; ++p) ai[p] = xi[ty + 16 * p][c];
#pragma unroll
        for (int q = 0; q < 4; ++q) aj[q] = xj[tx + 16 * q][c];
#pragma unroll
        for (int p = 0; p < 4; ++p)
#pragma unroll
            for (int q = 0; q < 4; ++q) {
                double d = ai[p] - aj[q];
                amax[p][q] = fmax(amax[p][q], fabs(d));
                adot[p][q] = fma(ai[p], aj[q], adot[p][q]);
            }
    }

#pragma unroll
    for (int p = 0; p < 4; ++p) {
        int li = ty + 16 * p;
        int ii = i0 + li;
        double rri = ri_[li], mmi = mi[li], ssi = si[li];
#pragma unroll
        for (int q = 0; q < 4; ++q) {
            int lj = tx + 16 * q;
            int jj = j0 + lj;
            double dot = adot[p][q];
            double d2  = rri + rj_[lj] - 2.0 * dot;
            double e   = (ii == jj) ? 0.0 : sqrt(fmax(d2, 0.0));
            double cc  = (dot - 64.0 * mmi * mj[lj]) * ssi * sj[lj];
            cc = fmin(1.0, fmax(-1.0, cc));
            size_t idx = (size_t)b * S + (size_t)ii * N + jj;
            E[idx]  = e;
            Ch[idx] = amax[p][q];
            Cc[idx] = cc;
        }
    }
}

// ---------------------------------------------------------------------------
// K2: C = scale * A * B^T (fp64, MFMA). 64x64 tile, 4 waves x 32x32 quadrant,
// LDS DOUBLE-BUFFERED (one barrier per K-iter), BK=32.
__global__ __launch_bounds__(256) void k_gemm_nt(const double* __restrict__ A,
                                                 const double* __restrict__ Bm,
                                                 double* __restrict__ Cm,
                                                 double scale) {
    int b = blockIdx.z;
    const double* Ab = A  + (size_t)b * S;
    const double* Bb = Bm + (size_t)b * S;
    double*       Cb = Cm + (size_t)b * S;
    int i0 = blockIdx.y * 64, j0 = blockIdx.x * 64;

    __shared__ double At[2][64][33];
    __shared__ double Bt[2][64][33];

    int t    = threadIdx.x;
    int lane = t & 63;
    int w    = t >> 6;
    int wr   = (w >> 1) * 32;
    int wc   = (w & 1) * 32;
    int fm   = lane & 15;
    int fk   = lane >> 4;

    int sr = t >> 2, sc0 = (t & 3) * 8;

    d4 acc00 = {0.0, 0.0, 0.0, 0.0};
    d4 acc01 = acc00, acc10 = acc00, acc11 = acc00;

    const double* ap = Ab + (size_t)(i0 + sr) * N + sc0;
    const double* bp = Bb + (size_t)(j0 + sr) * N + sc0;

    double pa[8], pb[8];
#pragma unroll
    for (int m = 0; m < 8; ++m) { pa[m] = ap[m]; pb[m] = bp[m]; }
#pragma unroll
    for (int m = 0; m < 8; ++m) { At[0][sr][sc0 + m] = pa[m]; Bt[0][sr][sc0 + m] = pb[m]; }
    __syncthreads();

    int cur = 0;
    for (int k0 = 0; k0 < N; k0 += 32) {
        bool has_next = (k0 + 32 < N);
        if (has_next) {
            ap += 32; bp += 32;
#pragma unroll
            for (int m = 0; m < 8; ++m) { pa[m] = ap[m]; pb[m] = bp[m]; }
        }
#pragma unroll
        for (int kq = 0; kq < 8; ++kq) {
            int kk = kq * 4 + fk;
            double a0 = At[cur][wr + fm][kk];
            double a1 = At[cur][wr + 16 + fm][kk];
            double b0 = Bt[cur][wc + fm][kk];
            double b1 = Bt[cur][wc + 16 + fm][kk];
            acc00 = __builtin_amdgcn_mfma_f64_16x16x4f64(a0, b0, acc00, 0, 0, 0);
            acc01 = __builtin_amdgcn_mfma_f64_16x16x4f64(a0, b1, acc01, 0, 0, 0);
            acc10 = __builtin_amdgcn_mfma_f64_16x16x4f64(a1, b0, acc10, 0, 0, 0);
            acc11 = __builtin_amdgcn_mfma_f64_16x16x4f64(a1, b1, acc11, 0, 0, 0);
        }
        if (has_next) {
            int nxt = cur ^ 1;
#pragma unroll
            for (int m = 0; m < 8; ++m) { At[nxt][sr][sc0 + m] = pa[m]; Bt[nxt][sr][sc0 + m] = pb[m]; }
            __syncthreads();
            cur = nxt;
        }
    }
    int r0 = i0 + wr + 4 * fk;
    int c0 = j0 + wc + fm;
#pragma unroll
    for (int r = 0; r < 4; ++r) {
        Cb[(size_t)(r0 + r)      * N + c0]      = acc00[r] * scale;
        Cb[(size_t)(r0 + r)      * N + c0 + 16] = acc01[r] * scale;
        Cb[(size_t)(r0 + 16 + r) * N + c0]      = acc10[r] * scale;
        Cb[(size_t)(r0 + 16 + r) * N + c0 + 16] = acc11[r] * scale;
    }
}

// ---------------------------------------------------------------------------
// K4: W = A * B (fp64, MFMA) + key32 epilogue. Double-buffered + EXACT
// zero-skip: attn rows are mostly exact 0.0 (softmax underflow) -> skip MFMA
// quads whose A-fragments are all 0.0 (bitwise-identical result: fma(0,c,acc)
// == acc for finite c, and a +0.0-initialized acc never becomes -0.0).
// Also zeroes the select kernel's grid barrier.
__global__ __launch_bounds__(256) void k_gemm_nn(const double* __restrict__ A,
                                                 const double* __restrict__ Bm,
                                                 double* __restrict__ Wm,
                                                 unsigned int* __restrict__ kq_out,
                                                 unsigned int* __restrict__ bar) {
    if (threadIdx.x == 0 && blockIdx.x == 0 && blockIdx.y == 0 && blockIdx.z == 0)
        bar[0] = 0u;

    int b = blockIdx.z;
    const double* Ab = A  + (size_t)b * S;
    const double* Bb = Bm + (size_t)b * S;
    double*       Wb = Wm + (size_t)b * S;
    unsigned int* kb = kq_out + (size_t)b * S;
    int i0 = blockIdx.y * 64, j0 = blockIdx.x * 64;

    __shared__ double At[2][64][33];
    __shared__ double Bt[2][32][65];

    int t    = threadIdx.x;
    int lane = t & 63;
    int w    = t >> 6;
    int wr   = (w >> 1) * 32;
    int wc   = (w & 1) * 32;
    int fm   = lane & 15;
    int fk   = lane >> 4;

    int sr = t >> 2, sc0 = (t & 3) * 8;   // A staging: 64 rows x 32 k
    int br = t >> 3, bc = (t & 7) * 8;    // B staging: 32 k x 64 cols

    d4 acc00 = {0.0, 0.0, 0.0, 0.0};
    d4 acc01 = acc00, acc10 = acc00, acc11 = acc00;

    const double* ap = Ab + (size_t)(i0 + sr) * N + sc0;
    const double* bp = Bb + (size_t)br * N + j0 + bc;

    double pa[8], pb[8];
#pragma unroll
    for (int m = 0; m < 8; ++m) { pa[m] = ap[m]; pb[m] = bp[m]; }
#pragma unroll
    for (int m = 0; m < 8; ++m) { At[0][sr][sc0 + m] = pa[m]; Bt[0][br][bc + m] = pb[m]; }
    __syncthreads();

    int cur = 0;
    for (int k0 = 0; k0 < N; k0 += 32) {
        bool has_next = (k0 + 32 < N);
        if (has_next) {
            ap += 32; bp += (size_t)32 * N;
#pragma unroll
            for (int m = 0; m < 8; ++m) { pa[m] = ap[m]; pb[m] = bp[m]; }
        }
#pragma unroll
        for (int kq = 0; kq < 8; ++kq) {
            int kk = kq * 4 + fk;
            double a0 = At[cur][wr + fm][kk];
            double a1 = At[cur][wr + 16 + fm][kk];
            if (__any((a0 != 0.0) || (a1 != 0.0))) {
                double b0 = Bt[cur][kk][wc + fm];
                double b1 = Bt[cur][kk][wc + 16 + fm];
                acc00 = __builtin_amdgcn_mfma_f64_16x16x4f64(a0, b0, acc00, 0, 0, 0);
                acc01 = __builtin_amdgcn_mfma_f64_16x16x4f64(a0, b1, acc01, 0, 0, 0);
                acc10 = __builtin_amdgcn_mfma_f64_16x16x4f64(a1, b0, acc10, 0, 0, 0);
                acc11 = __builtin_amdgcn_mfma_f64_16x16x4f64(a1, b1, acc11, 0, 0, 0);
            }
        }
        if (has_next) {
            int nxt = cur ^ 1;
#pragma unroll
            for (int m = 0; m < 8; ++m) { At[nxt][sr][sc0 + m] = pa[m]; Bt[nxt][br][bc + m] = pb[m]; }
            __syncthreads();
            cur = nxt;
        }
    }
    int r0 = i0 + wr + 4 * fk;
    int c0 = j0 + wc + fm;
#pragma unroll
    for (int r = 0; r < 4; ++r) {
        double w00 = acc00[r], w01 = acc01[r], w10 = acc10[r], w11 = acc11[r];
        size_t i00 = (size_t)(r0 + r)      * N + c0;
        size_t i01 = (size_t)(r0 + r)      * N + c0 + 16;
        size_t i10 = (size_t)(r0 + 16 + r) * N + c0;
        size_t i11 = (size_t)(r0 + 16 + r) * N + c0 + 16;
        Wb[i00] = w00; kb[i00] = (unsigned int)(d2key(w00) >> 32);
        Wb[i01] = w01; kb[i01] = (unsigned int)(d2key(w01) >> 32);
        Wb[i10] = w10; kb[i10] = (unsigned int)(d2key(w10) >> 32);
        Wb[i11] = w11; kb[i11] = (unsigned int)(d2key(w11) >> 32);
    }
}

// ---------------------------------------------------------------------------
// K3: fp64 row softmax. Wave per row, shuffle-only; 512 wgs.
__global__ __launch_bounds__(256) void k_softmax(double* __restrict__ L) {
    int row = (blockIdx.x << 2) + (threadIdx.x >> 6);
    int ln  = threadIdx.x & 63;
    double* p = L + (size_t)row * N;

    double v[16];
#pragma unroll
    for (int q = 0; q < 16; ++q) v[q] = p[ln + 64 * q];

    double mx = v[0];
#pragma unroll
    for (int q = 1; q < 16; ++q) mx = fmax(mx, v[q]);
#pragma unroll
    for (int off = 32; off >= 1; off >>= 1) mx = fmax(mx, __shfl_xor(mx, off));

    double s = 0.0;
#pragma unroll
    for (int q = 0; q < 16; ++q) { v[q] = exp(v[q] - mx); s += v[q]; }
#pragma unroll
    for (int off = 32; off >= 1; off >>= 1) s += __shfl_xor(s, off);

#pragma unroll
    for (int q = 0; q < 16; ++q) p[ln + 64 * q] = v[q] / s;
}

// ---------------------------------------------------------------------------
// K5: the ENTIRE selection in one kernel. Grid = 256 blocks (one per CU,
// co-residency by capacity), software grid barrier (cumulative counter,
// zeroed by k_gemm_nn). 4x 8-bit radix passes on key32 (redundant per-block
// scans avoid extra barriers), eq-collect, refine (2 blocks), final mask.
__device__ __forceinline__ void gridbar(unsigned int* bar, unsigned int* phase) {
    __syncthreads();
    if (threadIdx.x == 0) {
        __threadfence();
        unsigned int target = (++(*phase)) * (unsigned int)NSELBLK;
        __hip_atomic_fetch_add(bar, 1u, __ATOMIC_RELAXED, __HIP_MEMORY_SCOPE_AGENT);
        while (__hip_atomic_load(bar, __ATOMIC_RELAXED, __HIP_MEMORY_SCOPE_AGENT) < target)
            __builtin_amdgcn_s_sleep(1);
        __threadfence();
    }
    __syncthreads();
}

__global__ __launch_bounds__(256) void k_select(const unsigned int* __restrict__ key32,
                                                const double* __restrict__ W,
                                                int* __restrict__ hist,      // 4*2*256 ints
                                                int* __restrict__ eqbuf,
                                                unsigned int* __restrict__ sc,
                                                unsigned int* __restrict__ bar,
                                                float* __restrict__ out) {
    int blk = blockIdx.x, t = threadIdx.x;
    int b  = blk >> 7;            // 128 blocks per batch
    int lb = blk & 127;
    unsigned int phase = 0;

    __shared__ int lh[256];
    __shared__ unsigned int s_pref, s_kneed;

    // phase 0: zero scratch (hist: 2048 ints; eq counters)
    if (blk < 8) hist[blk * 256 + t] = 0;
    if (blk == 8 && t < BB) eqbuf[t * ESTRIDE] = 0;
    gridbar(bar, &phase);

    const uint4* k4 = (const uint4*)(key32 + (size_t)b * S);
    unsigned int pref = 0, kneed = (unsigned int)KSEL;

    for (int p = 0; p < 4; ++p) {
        int shift = 24 - 8 * p;
        lh[t] = 0;
        __syncthreads();
        unsigned int prefh = (p == 0) ? 0u : (pref >> (shift + 8));
        for (int it = 0; it < 8; ++it) {
            int g4 = (it * 128 + lb) * 256 + t;
            uint4 kv = k4[g4];
            unsigned int ks[4] = {kv.x, kv.y, kv.z, kv.w};
#pragma unroll
            for (int c = 0; c < 4; ++c) {
                bool match = (p == 0) || ((ks[c] >> (shift + 8)) == prefh);
                if (match) atomicAdd(&lh[(ks[c] >> shift) & 255u], 1);
            }
        }
        __syncthreads();
        atomicAdd(&hist[(p * 2 + b) * 256 + t], lh[t]);
        gridbar(bar, &phase);
        // redundant scan: coalesced load to LDS, thread 0 walks it
        lh[t] = hist[(p * 2 + b) * 256 + t];
        __syncthreads();
        if (t == 0) {
            unsigned int cum = 0; int bucket = 0;
            for (int i = 255; i >= 0; --i) {
                unsigned int h = (unsigned int)lh[i];
                if (cum + h >= kneed) { bucket = i; break; }
                cum += h;
            }
            s_pref  = pref | ((unsigned int)bucket << shift);
            s_kneed = kneed - cum;
        }
        __syncthreads();
        pref = s_pref; kneed = s_kneed;
        __syncthreads();
    }

    // eq-collect: (low32(W), idx) for key32 == T32
    for (int it = 0; it < 8; ++it) {
        int g4 = (it * 128 + lb) * 256 + t;
        uint4 kv = k4[g4];
        unsigned int ks[4] = {kv.x, kv.y, kv.z, kv.w};
#pragma unroll
        for (int c = 0; c < 4; ++c) {
            if (ks[c] == pref) {
                int pos = atomicAdd(&eqbuf[b * ESTRIDE], 1);
                if (pos < EQCAP) {
                    int s = g4 * 4 + c;
                    unsigned int low = (unsigned int)d2key(W[(size_t)b * S + s]);
                    eqbuf[b * ESTRIDE + 1 + 2 * pos] = (int)low;
                    eqbuf[b * ESTRIDE + 2 + 2 * pos] = s;
                }
            }
        }
    }
    gridbar(bar, &phase);

    // refine: one block per batch (lb == 0)
    if (lb == 0) {
        const int* eb = eqbuf + b * ESTRIDE;
        int cnt = eb[0];
        if (cnt > EQCAP) cnt = EQCAP;
        unsigned int rpref = 0, rkneed = kneed;
        for (int shift = 24; shift >= 0; shift -= 8) {
            lh[t] = 0;
            __syncthreads();
            unsigned int ph = (shift == 24) ? 0u : (rpref >> (shift + 8));
            for (int e = t; e < cnt; e += 256) {
                unsigned int low = (unsigned int)eb[1 + 2 * e];
                bool match = (shift == 24) || ((low >> (shift + 8)) == ph);
                if (match) atomicAdd(&lh[(low >> shift) & 255u], 1);
            }
            __syncthreads();
            if (t == 0) {
                unsigned int cum = 0; int bucket = 0;
                for (int i = 255; i >= 0; --i) {
                    unsigned int h = (unsigned int)lh[i];
                    if (cum + h >= rkneed) { bucket = i; break; }
                    cum += h;
                }
                s_pref  = rpref | ((unsigned int)bucket << shift);
                s_kneed = rkneed - cum;
            }
            __syncthreads();
            rpref = s_pref; rkneed = s_kneed;
            __syncthreads();
        }
        unsigned int TL = rpref;
        unsigned int ipref = 0;
        for (int shift = 16; shift >= 0; shift -= 8) {
            lh[t] = 0;
            __syncthreads();
            unsigned int ph = (shift == 16) ? 0u : (ipref >> (shift + 8));
            for (int e = t; e < cnt; e += 256) {
                unsigned int low = (unsigned int)eb[1 + 2 * e];
                if (low != TL) continue;
                unsigned int idx = (unsigned int)eb[2 + 2 * e];
                bool match = (shift == 16) || ((idx >> (shift + 8)) == ph);
                if (match) atomicAdd(&lh[(idx >> shift) & 255u], 1);
            }
            __syncthreads();
            if (t == 0) {
                unsigned int cum = 0; int bucket = 0;
                for (int i = 255; i >= 0; --i) {
                    unsigned int h = (unsigned int)lh[i];
                    if (cum + h >= rkneed) { bucket = i; break; }
                    cum += h;
                }
                s_pref  = ipref | ((unsigned int)bucket << shift);
                s_kneed = rkneed - cum;
            }
            __syncthreads();
            ipref = s_pref; rkneed = s_kneed;
            __syncthreads();
        }
        if (t == 0) { sc[2 * b] = TL; sc[2 * b + 1] = ipref; }
    }
    gridbar(bar, &phase);

    // final mask
    unsigned int TL   = sc[2 * b];
    unsigned int sCut = sc[2 * b + 1];
    float4* out4 = (float4*)(out + (size_t)b * S);
    for (int it = 0; it < 8; ++it) {
        int g4 = (it * 128 + lb) * 256 + t;
        uint4 kv = k4[g4];
        unsigned int ks[4] = {kv.x, kv.y, kv.z, kv.w};
        float ov[4];
#pragma unroll
        for (int c = 0; c < 4; ++c) {
            float v = 0.0f;
            if (ks[c] > pref) {
                v = 1.0f;
            } else if (ks[c] == pref) {
                int s = g4 * 4 + c;
                unsigned int low = (unsigned int)d2key(W[(size_t)b * S + s]);
                v = (low > TL || (low == TL && (unsigned int)s >= sCut)) ? 1.0f : 0.0f;
            }
            ov[c] = v;
        }
        out4[g4] = make_float4(ov[0], ov[1], ov[2], ov[3]);
    }
}

// ---------------------------------------------------------------------------
extern "C" void kernel_launch(void* const* d_in, const int* in_sizes, int n_in,
                              void* d_out, int out_size, void* d_ws, size_t ws_size,
                              hipStream_t stream) {
    const float* x = (const float*)d_in[0];
    float* out = (float*)d_out;

    char* ws = (char*)d_ws;
    size_t off = 0;
    auto alloc = [&](size_t bytes) -> void* {
        void* p = ws + off;
        off += (bytes + 255) & ~(size_t)255;
        return p;
    };

    double* E     = (double*)alloc((size_t)BB * S * sizeof(double));       // 16 MB
    double* Ch    = (double*)alloc((size_t)BB * S * sizeof(double));       // 16 MB
    double* Cc    = (double*)alloc((size_t)BB * S * sizeof(double));       // 16 MB
    double* L     = (double*)alloc((size_t)BB * S * sizeof(double));       // 16 MB
    unsigned int* key32 = (unsigned int*)alloc((size_t)BB * S * sizeof(unsigned int)); // 8 MB
    double* W     = E;  // E dead after gemm_nt -> reuse for weighted
    unsigned int* sc  = (unsigned int*)alloc(64);
    unsigned int* bar = (unsigned int*)alloc(64);
    int* hist  = (int*)alloc(4 * 2 * 256 * sizeof(int));
    int* eqbuf = (int*)alloc((size_t)BB * ESTRIDE * sizeof(int));          // ~1 MB

    // 1) pairwise adjacencies (fused per-row stats)
    k_pairwise<<<dim3(N / 64, N / 64, BB), 256, 0, stream>>>(x, E, Ch, Cc);

    // 2) logits = (E @ Ch^T) * 1/8   (MFMA f64, double-buffered)
    k_gemm_nt<<<dim3(N / 64, N / 64, BB), 256, 0, stream>>>(E, Ch, L, 0.125);

    // 3) softmax rows
    k_softmax<<<512, 256, 0, stream>>>(L);

    // 4) weighted = attn @ Cc + key32 epilogue (zero-skip; zeroes bar)
    k_gemm_nn<<<dim3(N / 64, N / 64, BB), 256, 0, stream>>>(L, Cc, W, key32, bar);

    // 5) entire selection: radix select + tie refine + mask, one kernel
    k_select<<<NSELBLK, 256, 0, stream>>>(key32, W, hist, eqbuf, sc, bar, out);
}

// Round 7
// 397.385 us; speedup vs baseline: 3.9490x; 1.1318x over previous
//
#include <hip/hip_runtime.h>
#include <hip/hip_bf16.h>

// Problem constants (from setup_inputs: x = [2, 1024, 64] fp32)
constexpr int BB = 2;
constexpr int N  = 1024;
constexpr int C  = 64;
constexpr int S  = N * N;          // 1048576 = 2^20
constexpr int KSEL = S / 6;        // 174762 entries set to 1 per batch
constexpr int EQCAP   = 1 << 19;   // tie-list capacity per batch (13x margin)
constexpr int ESTRIDE = 1 + 2 * EQCAP;   // u32s: [cnt][low32,idx]*EQCAP
constexpr int NSELBLK = 256;       // select grid == #CUs -> co-resident

typedef double d4 __attribute__((ext_vector_type(4)));

// Order-preserving uint64 mapping of fp64 (monotone: a<b <=> key(a)<key(b))
__device__ __forceinline__ unsigned long long d2key(double d) {
    unsigned long long u = (unsigned long long)__double_as_longlong(d);
    return (u & 0x8000000000000000ULL) ? ~u : (u | 0x8000000000000000ULL);
}

// Device-scope helpers (execute at coherence point; no L2 dirtiness).
__device__ __forceinline__ unsigned int aload(unsigned int* p) {
    return __hip_atomic_fetch_add(p, 0u, __ATOMIC_RELAXED, __HIP_MEMORY_SCOPE_AGENT);
}
__device__ __forceinline__ void astore(unsigned int* p, unsigned int v) {
    (void)__hip_atomic_exchange(p, v, __ATOMIC_RELAXED, __HIP_MEMORY_SCOPE_AGENT);
}

// ---------------------------------------------------------------------------
// K1: pairwise adjacencies with fused per-row stats. 64x64 tile (512 wgs).
__global__ __launch_bounds__(256) void k_pairwise(const float* __restrict__ x,
                                                  double* __restrict__ E,
                                                  double* __restrict__ Ch,
                                                  double* __restrict__ Cc) {
    int b  = blockIdx.z;
    int i0 = blockIdx.y * 64;
    int j0 = blockIdx.x * 64;
    __shared__ double xi[64][65];
    __shared__ double xj[64][65];
    __shared__ double mi[64], ri_[64], si[64];
    __shared__ double mj[64], rj_[64], sj[64];

    int t  = threadIdx.x;
    int r  = t >> 2;
    int cb = (t & 3) * 16;
    const float* xb = x + (size_t)b * N * C;
    {
        const float4* pi = (const float4*)(xb + (size_t)(i0 + r) * C + cb);
        const float4* pj = (const float4*)(xb + (size_t)(j0 + r) * C + cb);
#pragma unroll
        for (int m4 = 0; m4 < 4; ++m4) {
            float4 fi = pi[m4], fj = pj[m4];
            xi[r][cb + 4 * m4 + 0] = (double)fi.x; xi[r][cb + 4 * m4 + 1] = (double)fi.y;
            xi[r][cb + 4 * m4 + 2] = (double)fi.z; xi[r][cb + 4 * m4 + 3] = (double)fi.w;
            xj[r][cb + 4 * m4 + 0] = (double)fj.x; xj[r][cb + 4 * m4 + 1] = (double)fj.y;
            xj[r][cb + 4 * m4 + 2] = (double)fj.z; xj[r][cb + 4 * m4 + 3] = (double)fj.w;
        }
    }
    __syncthreads();

    if (t < 128) {
        int row = t & 63;
        const double (*xs)[65] = (t < 64) ? xi : xj;
        double sum = 0.0, rr = 0.0;
#pragma unroll 8
        for (int c = 0; c < 64; ++c) { double v = xs[row][c]; sum += v; rr = fma(v, v, rr); }
        double m = sum / 64.0;
        double q = 0.0;
#pragma unroll 8
        for (int c = 0; c < 64; ++c) { double w = xs[row][c] - m; q = fma(w, w, q); }
        double sv = 1.0 / sqrt(q);
        if (t < 64) { mi[row] = m; ri_[row] = rr; si[row] = sv; }
        else        { mj[row] = m; rj_[row] = rr; sj[row] = sv; }
    }
    __syncthreads();

    int ty = t >> 4, tx = t & 15;
    double adot[4][4] = {};
    double amax[4][4] = {};
#pragma unroll 8
    for (int c = 0; c < 64; ++c) {
        double ai[4], aj[4];
#pragma unroll
        for (int p = 0; p < 4; ++p) ai[p] = xi[ty + 16 * p][c];
#pragma unroll
        for (int q = 0; q < 4; ++q) aj[q] = xj[tx + 16 * q][c];
#pragma unroll
        for (int p = 0; p < 4; ++p)
#pragma unroll
            for (int q = 0; q < 4; ++q) {
                double d = ai[p] - aj[q];
                amax[p][q] = fmax(amax[p][q], fabs(d));
                adot[p][q] = fma(ai[p], aj[q], adot[p][q]);
            }
    }

#pragma unroll
    for (int p = 0; p < 4; ++p) {
        int li = ty + 16 * p;
        int ii = i0 + li;
        double rri = ri_[li], mmi = mi[li], ssi = si[li];
#pragma unroll
        for (int q = 0; q < 4; ++q) {
            int lj = tx + 16 * q;
            int jj = j0 + lj;
            double dot = adot[p][q];
            double d2  = rri + rj_[lj] - 2.0 * dot;
            double e   = (ii == jj) ? 0.0 : sqrt(fmax(d2, 0.0));
            double cc  = (dot - 64.0 * mmi * mj[lj]) * ssi * sj[lj];
            cc = fmin(1.0, fmax(-1.0, cc));
            size_t idx = (size_t)b * S + (size_t)ii * N + jj;
            E[idx]  = e;
            Ch[idx] = amax[p][q];
            Cc[idx] = cc;
        }
    }
}

// ---------------------------------------------------------------------------
// K2: C = scale * A * B^T (fp64, MFMA). 64x64 tile, 4 waves x 32x32 quadrant,
// LDS double-buffered, BK=32.
__global__ __launch_bounds__(256) void k_gemm_nt(const double* __restrict__ A,
                                                 const double* __restrict__ Bm,
                                                 double* __restrict__ Cm,
                                                 double scale) {
    int b = blockIdx.z;
    const double* Ab = A  + (size_t)b * S;
    const double* Bb = Bm + (size_t)b * S;
    double*       Cb = Cm + (size_t)b * S;
    int i0 = blockIdx.y * 64, j0 = blockIdx.x * 64;

    __shared__ double At[2][64][33];
    __shared__ double Bt[2][64][33];

    int t    = threadIdx.x;
    int lane = t & 63;
    int w    = t >> 6;
    int wr   = (w >> 1) * 32;
    int wc   = (w & 1) * 32;
    int fm   = lane & 15;
    int fk   = lane >> 4;

    int sr = t >> 2, sc0 = (t & 3) * 8;

    d4 acc00 = {0.0, 0.0, 0.0, 0.0};
    d4 acc01 = acc00, acc10 = acc00, acc11 = acc00;

    const double* ap = Ab + (size_t)(i0 + sr) * N + sc0;
    const double* bp = Bb + (size_t)(j0 + sr) * N + sc0;

    double pa[8], pb[8];
#pragma unroll
    for (int m = 0; m < 8; ++m) { pa[m] = ap[m]; pb[m] = bp[m]; }
#pragma unroll
    for (int m = 0; m < 8; ++m) { At[0][sr][sc0 + m] = pa[m]; Bt[0][sr][sc0 + m] = pb[m]; }
    __syncthreads();

    int cur = 0;
    for (int k0 = 0; k0 < N; k0 += 32) {
        bool has_next = (k0 + 32 < N);
        if (has_next) {
            ap += 32; bp += 32;
#pragma unroll
            for (int m = 0; m < 8; ++m) { pa[m] = ap[m]; pb[m] = bp[m]; }
        }
#pragma unroll
        for (int kq = 0; kq < 8; ++kq) {
            int kk = kq * 4 + fk;
            double a0 = At[cur][wr + fm][kk];
            double a1 = At[cur][wr + 16 + fm][kk];
            double b0 = Bt[cur][wc + fm][kk];
            double b1 = Bt[cur][wc + 16 + fm][kk];
            acc00 = __builtin_amdgcn_mfma_f64_16x16x4f64(a0, b0, acc00, 0, 0, 0);
            acc01 = __builtin_amdgcn_mfma_f64_16x16x4f64(a0, b1, acc01, 0, 0, 0);
            acc10 = __builtin_amdgcn_mfma_f64_16x16x4f64(a1, b0, acc10, 0, 0, 0);
            acc11 = __builtin_amdgcn_mfma_f64_16x16x4f64(a1, b1, acc11, 0, 0, 0);
        }
        if (has_next) {
            int nxt = cur ^ 1;
#pragma unroll
            for (int m = 0; m < 8; ++m) { At[nxt][sr][sc0 + m] = pa[m]; Bt[nxt][sr][sc0 + m] = pb[m]; }
            __syncthreads();
            cur = nxt;
        }
    }
    int r0 = i0 + wr + 4 * fk;
    int c0 = j0 + wc + fm;
#pragma unroll
    for (int r = 0; r < 4; ++r) {
        Cb[(size_t)(r0 + r)      * N + c0]      = acc00[r] * scale;
        Cb[(size_t)(r0 + r)      * N + c0 + 16] = acc01[r] * scale;
        Cb[(size_t)(r0 + 16 + r) * N + c0]      = acc10[r] * scale;
        Cb[(size_t)(r0 + 16 + r) * N + c0 + 16] = acc11[r] * scale;
    }
}

// ---------------------------------------------------------------------------
// K4: W = A * B (fp64, MFMA) + key32 epilogue. Double-buffered. Block (0,0,0)
// zeroes ALL of k_select's scratch (bar, hist, eq counters) via plain stores —
// the kernel-end release flush makes them visible & clean device-wide.
__global__ __launch_bounds__(256) void k_gemm_nn(const double* __restrict__ A,
                                                 const double* __restrict__ Bm,
                                                 double* __restrict__ Wm,
                                                 unsigned int* __restrict__ kq_out,
                                                 unsigned int* __restrict__ bar,
                                                 int* __restrict__ hist,
                                                 unsigned int* __restrict__ eqbuf) {
    if (blockIdx.x == 0 && blockIdx.y == 0 && blockIdx.z == 0) {
        int tt = threadIdx.x;
        if (tt == 0) bar[0] = 0u;
        for (int i = tt; i < 2048; i += 256) hist[i] = 0;
        if (tt < BB) eqbuf[(size_t)tt * ESTRIDE] = 0u;
    }

    int b = blockIdx.z;
    const double* Ab = A  + (size_t)b * S;
    const double* Bb = Bm + (size_t)b * S;
    double*       Wb = Wm + (size_t)b * S;
    unsigned int* kb = kq_out + (size_t)b * S;
    int i0 = blockIdx.y * 64, j0 = blockIdx.x * 64;

    __shared__ double At[2][64][33];
    __shared__ double Bt[2][32][65];

    int t    = threadIdx.x;
    int lane = t & 63;
    int w    = t >> 6;
    int wr   = (w >> 1) * 32;
    int wc   = (w & 1) * 32;
    int fm   = lane & 15;
    int fk   = lane >> 4;

    int sr = t >> 2, sc0 = (t & 3) * 8;   // A staging: 64 rows x 32 k
    int br = t >> 3, bc = (t & 7) * 8;    // B staging: 32 k x 64 cols

    d4 acc00 = {0.0, 0.0, 0.0, 0.0};
    d4 acc01 = acc00, acc10 = acc00, acc11 = acc00;

    const double* ap = Ab + (size_t)(i0 + sr) * N + sc0;
    const double* bp = Bb + (size_t)br * N + j0 + bc;

    double pa[8], pb[8];
#pragma unroll
    for (int m = 0; m < 8; ++m) { pa[m] = ap[m]; pb[m] = bp[m]; }
#pragma unroll
    for (int m = 0; m < 8; ++m) { At[0][sr][sc0 + m] = pa[m]; Bt[0][br][bc + m] = pb[m]; }
    __syncthreads();

    int cur = 0;
    for (int k0 = 0; k0 < N; k0 += 32) {
        bool has_next = (k0 + 32 < N);
        if (has_next) {
            ap += 32; bp += (size_t)32 * N;
#pragma unroll
            for (int m = 0; m < 8; ++m) { pa[m] = ap[m]; pb[m] = bp[m]; }
        }
#pragma unroll
        for (int kq = 0; kq < 8; ++kq) {
            int kk = kq * 4 + fk;
            double a0 = At[cur][wr + fm][kk];
            double a1 = At[cur][wr + 16 + fm][kk];
            double b0 = Bt[cur][kk][wc + fm];
            double b1 = Bt[cur][kk][wc + 16 + fm];
            acc00 = __builtin_amdgcn_mfma_f64_16x16x4f64(a0, b0, acc00, 0, 0, 0);
            acc01 = __builtin_amdgcn_mfma_f64_16x16x4f64(a0, b1, acc01, 0, 0, 0);
            acc10 = __builtin_amdgcn_mfma_f64_16x16x4f64(a1, b0, acc10, 0, 0, 0);
            acc11 = __builtin_amdgcn_mfma_f64_16x16x4f64(a1, b1, acc11, 0, 0, 0);
        }
        if (has_next) {
            int nxt = cur ^ 1;
#pragma unroll
            for (int m = 0; m < 8; ++m) { At[nxt][sr][sc0 + m] = pa[m]; Bt[nxt][br][bc + m] = pb[m]; }
            __syncthreads();
            cur = nxt;
        }
    }
    int r0 = i0 + wr + 4 * fk;
    int c0 = j0 + wc + fm;
#pragma unroll
    for (int r = 0; r < 4; ++r) {
        double w00 = acc00[r], w01 = acc01[r], w10 = acc10[r], w11 = acc11[r];
        size_t i00 = (size_t)(r0 + r)      * N + c0;
        size_t i01 = (size_t)(r0 + r)      * N + c0 + 16;
        size_t i10 = (size_t)(r0 + 16 + r) * N + c0;
        size_t i11 = (size_t)(r0 + 16 + r) * N + c0 + 16;
        Wb[i00] = w00; kb[i00] = (unsigned int)(d2key(w00) >> 32);
        Wb[i01] = w01; kb[i01] = (unsigned int)(d2key(w01) >> 32);
        Wb[i10] = w10; kb[i10] = (unsigned int)(d2key(w10) >> 32);
        Wb[i11] = w11; kb[i11] = (unsigned int)(d2key(w11) >> 32);
    }
}

// ---------------------------------------------------------------------------
// K3: fp64 row softmax. Wave per row, shuffle-only; 512 wgs.
__global__ __launch_bounds__(256) void k_softmax(double* __restrict__ L) {
    int row = (blockIdx.x << 2) + (threadIdx.x >> 6);
    int ln  = threadIdx.x & 63;
    double* p = L + (size_t)row * N;

    double v[16];
#pragma unroll
    for (int q = 0; q < 16; ++q) v[q] = p[ln + 64 * q];

    double mx = v[0];
#pragma unroll
    for (int q = 1; q < 16; ++q) mx = fmax(mx, v[q]);
#pragma unroll
    for (int off = 32; off >= 1; off >>= 1) mx = fmax(mx, __shfl_xor(mx, off));

    double s = 0.0;
#pragma unroll
    for (int q = 0; q < 16; ++q) { v[q] = exp(v[q] - mx); s += v[q]; }
#pragma unroll
    for (int off = 32; off >= 1; off >>= 1) s += __shfl_xor(s, off);

#pragma unroll
    for (int q = 0; q < 16; ++q) p[ln + 64 * q] = v[q] / s;
}

// ---------------------------------------------------------------------------
// K5: fused selection. 256 co-resident blocks, 6 grid barriers.
// NO __threadfence (no L2 writeback): all cross-block data moves via
// device-scope atomic RMWs (coherence-point ops); barrier = vmcnt drain +
// relaxed fetch_add + backoff spin.
__device__ __forceinline__ void gridbar(unsigned int* bar, unsigned int* phase) {
    __syncthreads();
    if (threadIdx.x == 0) {
        asm volatile("s_waitcnt vmcnt(0)" ::: "memory");
        unsigned int target = (++(*phase)) * (unsigned int)NSELBLK;
        __hip_atomic_fetch_add(bar, 1u, __ATOMIC_RELAXED, __HIP_MEMORY_SCOPE_AGENT);
        while (aload(bar) < target) __builtin_amdgcn_s_sleep(8);
        asm volatile("" ::: "memory");
    }
    __syncthreads();
}

__global__ __launch_bounds__(256) void k_select(const unsigned int* __restrict__ key32,
                                                const double* __restrict__ W,
                                                int* __restrict__ hist,      // 4*2*256 ints
                                                unsigned int* __restrict__ eqbuf,
                                                unsigned int* __restrict__ sc,
                                                unsigned int* __restrict__ bar,
                                                float* __restrict__ out) {
    int blk = blockIdx.x, t = threadIdx.x;
    int b  = blk >> 7;            // 128 blocks per batch
    int lb = blk & 127;
    unsigned int phase = 0;

    __shared__ int lh[256];
    __shared__ unsigned int s_pref, s_kneed;

    const uint4* k4 = (const uint4*)(key32 + (size_t)b * S);
    unsigned int pref = 0, kneed = (unsigned int)KSEL;

    // ---- 4 radix passes on key32 (scratch pre-zeroed by k_gemm_nn) ----
    for (int p = 0; p < 4; ++p) {
        int shift = 24 - 8 * p;
        lh[t] = 0;
        __syncthreads();
        unsigned int prefh = (p == 0) ? 0u : (pref >> (shift + 8));
        for (int it = 0; it < 8; ++it) {
            int g4 = (it * 128 + lb) * 256 + t;
            uint4 kv = k4[g4];
            unsigned int ks[4] = {kv.x, kv.y, kv.z, kv.w};
#pragma unroll
            for (int c = 0; c < 4; ++c) {
                bool match = (p == 0) || ((ks[c] >> (shift + 8)) == prefh);
                if (match) atomicAdd(&lh[(ks[c] >> shift) & 255u], 1);
            }
        }
        __syncthreads();
        if (lh[t] != 0)
            __hip_atomic_fetch_add((unsigned int*)&hist[(p * 2 + b) * 256 + t],
                                   (unsigned int)lh[t], __ATOMIC_RELAXED,
                                   __HIP_MEMORY_SCOPE_AGENT);
        gridbar(bar, &phase);
        // redundant per-block scan (coherent read via fetch_add 0)
        lh[t] = (int)aload((unsigned int*)&hist[(p * 2 + b) * 256 + t]);
        __syncthreads();
        if (t == 0) {
            unsigned int cum = 0; int bucket = 0;
            for (int i = 255; i >= 0; --i) {
                unsigned int h = (unsigned int)lh[i];
                if (cum + h >= kneed) { bucket = i; break; }
                cum += h;
            }
            s_pref  = pref | ((unsigned int)bucket << shift);
            s_kneed = kneed - cum;
        }
        __syncthreads();
        pref = s_pref; kneed = s_kneed;
        __syncthreads();
    }

    // ---- eq-collect: (low32(W), idx) for key32 == T32, via RMW stores ----
    unsigned int* ecnt = &eqbuf[(size_t)b * ESTRIDE];
    for (int it = 0; it < 8; ++it) {
        int g4 = (it * 128 + lb) * 256 + t;
        uint4 kv = k4[g4];
        unsigned int ks[4] = {kv.x, kv.y, kv.z, kv.w};
#pragma unroll
        for (int c = 0; c < 4; ++c) {
            if (ks[c] == pref) {
                unsigned int pos = __hip_atomic_fetch_add(ecnt, 1u, __ATOMIC_RELAXED,
                                                          __HIP_MEMORY_SCOPE_AGENT);
                if (pos < (unsigned int)EQCAP) {
                    int s = g4 * 4 + c;
                    unsigned int low = (unsigned int)d2key(W[(size_t)b * S + s]);
                    astore(&eqbuf[(size_t)b * ESTRIDE + 1 + 2 * pos], low);
                    astore(&eqbuf[(size_t)b * ESTRIDE + 2 + 2 * pos], (unsigned int)s);
                }
            }
        }
    }
    gridbar(bar, &phase);

    // ---- refine (one block per batch): 4 passes low32 + 3 passes idx ----
    if (lb == 0) {
        const unsigned int* eb = &eqbuf[(size_t)b * ESTRIDE];
        unsigned int cnt = aload(ecnt);
        if (cnt > (unsigned int)EQCAP) cnt = EQCAP;
        unsigned int rpref = 0, rkneed = kneed;
        for (int shift = 24; shift >= 0; shift -= 8) {
            lh[t] = 0;
            __syncthreads();
            unsigned int ph = (shift == 24) ? 0u : (rpref >> (shift + 8));
            for (unsigned int e = t; e < cnt; e += 256) {
                unsigned int low = eb[1 + 2 * e];          // plain load: line only
                bool match = (shift == 24) || ((low >> (shift + 8)) == ph);  // ever RMW-written
                if (match) atomicAdd(&lh[(low >> shift) & 255u], 1);
            }
            __syncthreads();
            if (t == 0) {
                unsigned int cum = 0; int bucket = 0;
                for (int i = 255; i >= 0; --i) {
                    unsigned int h = (unsigned int)lh[i];
                    if (cum + h >= rkneed) { bucket = i; break; }
                    cum += h;
                }
                s_pref  = rpref | ((unsigned int)bucket << shift);
                s_kneed = rkneed - cum;
            }
            __syncthreads();
            rpref = s_pref; rkneed = s_kneed;
            __syncthreads();
        }
        unsigned int TL = rpref;
        unsigned int ipref = 0;
        for (int shift = 16; shift >= 0; shift -= 8) {
            lh[t] = 0;
            __syncthreads();
            unsigned int ph = (shift == 16) ? 0u : (ipref >> (shift + 8));
            for (unsigned int e = t; e < cnt; e += 256) {
                unsigned int low = eb[1 + 2 * e];
                if (low != TL) continue;
                unsigned int idx = eb[2 + 2 * e];
                bool match = (shift == 16) || ((idx >> (shift + 8)) == ph);
                if (match) atomicAdd(&lh[(idx >> shift) & 255u], 1);
            }
            __syncthreads();
            if (t == 0) {
                unsigned int cum = 0; int bucket = 0;
                for (int i = 255; i >= 0; --i) {
                    unsigned int h = (unsigned int)lh[i];
                    if (cum + h >= rkneed) { bucket = i; break; }
                    cum += h;
                }
                s_pref  = ipref | ((unsigned int)bucket << shift);
                s_kneed = rkneed - cum;
            }
            __syncthreads();
            ipref = s_pref; rkneed = s_kneed;
            __syncthreads();
        }
        if (t == 0) { astore(&sc[2 * b], TL); astore(&sc[2 * b + 1], ipref); }
    }
    gridbar(bar, &phase);

    // ---- final mask ----
    unsigned int TL   = aload(&sc[2 * b]);
    unsigned int sCut = aload(&sc[2 * b + 1]);
    float4* out4 = (float4*)(out + (size_t)b * S);
    for (int it = 0; it < 8; ++it) {
        int g4 = (it * 128 + lb) * 256 + t;
        uint4 kv = k4[g4];
        unsigned int ks[4] = {kv.x, kv.y, kv.z, kv.w};
        float ov[4];
#pragma unroll
        for (int c = 0; c < 4; ++c) {
            float v = 0.0f;
            if (ks[c] > pref) {
                v = 1.0f;
            } else if (ks[c] == pref) {
                int s = g4 * 4 + c;
                unsigned int low = (unsigned int)d2key(W[(size_t)b * S + s]);
                v = (low > TL || (low == TL && (unsigned int)s >= sCut)) ? 1.0f : 0.0f;
            }
            ov[c] = v;
        }
        out4[g4] = make_float4(ov[0], ov[1], ov[2], ov[3]);
    }
}

// ---------------------------------------------------------------------------
extern "C" void kernel_launch(void* const* d_in, const int* in_sizes, int n_in,
                              void* d_out, int out_size, void* d_ws, size_t ws_size,
                              hipStream_t stream) {
    const float* x = (const float*)d_in[0];
    float* out = (float*)d_out;

    char* ws = (char*)d_ws;
    size_t off = 0;
    auto alloc = [&](size_t bytes) -> void* {
        void* p = ws + off;
        off += (bytes + 255) & ~(size_t)255;
        return p;
    };

    double* E     = (double*)alloc((size_t)BB * S * sizeof(double));       // 16 MB
    double* Ch    = (double*)alloc((size_t)BB * S * sizeof(double));       // 16 MB
    double* Cc    = (double*)alloc((size_t)BB * S * sizeof(double));       // 16 MB
    double* L     = (double*)alloc((size_t)BB * S * sizeof(double));       // 16 MB
    unsigned int* key32 = (unsigned int*)alloc((size_t)BB * S * sizeof(unsigned int)); // 8 MB
    double* W     = E;  // E dead after gemm_nt -> reuse for weighted
    unsigned int* sc  = (unsigned int*)alloc(64);
    unsigned int* bar = (unsigned int*)alloc(64);
    int* hist  = (int*)alloc(4 * 2 * 256 * sizeof(int));
    unsigned int* eqbuf = (unsigned int*)alloc((size_t)BB * ESTRIDE * sizeof(unsigned int)); // ~8.4 MB

    // 1) pairwise adjacencies (fused per-row stats)
    k_pairwise<<<dim3(N / 64, N / 64, BB), 256, 0, stream>>>(x, E, Ch, Cc);

    // 2) logits = (E @ Ch^T) * 1/8
    k_gemm_nt<<<dim3(N / 64, N / 64, BB), 256, 0, stream>>>(E, Ch, L, 0.125);

    // 3) softmax rows
    k_softmax<<<512, 256, 0, stream>>>(L);

    // 4) weighted = attn @ Cc + key32 epilogue (+ zeroes select scratch)
    k_gemm_nn<<<dim3(N / 64, N / 64, BB), 256, 0, stream>>>(L, Cc, W, key32, bar, hist, eqbuf);

    // 5) fused selection (6 fence-free grid barriers)
    k_select<<<NSELBLK, 256, 0, stream>>>(key32, W, hist, eqbuf, sc, bar, out);
}